// Round 11
// baseline (106.149 us; speedup 1.0000x reference)
//
#include <hip/hip_runtime.h>
#include <hip/hip_bf16.h>

// Eq4Net: permutation-equivariant 4th-order set network.
// T = x^{ox4} is rank-1 per channel: layer-1 pre-activations are
//   pre[s](k,l) = sum_d A_ij[s][d]*x_k[d]*x_l[d] + Bt_ij[k][s] + Gt2_ij[l][s].
// KB: per-tile eval (tables in LDS) -> T1 bf16 (L3-resident).
// K3: i/j marginals from T1, 4 threads per position (6-term quarter sums,
//     shfl-combined) for latency hiding; raw + contracted, bf16-packed.
// KD: pair/triple/quad tables from packed marginals.
// K5: loads its tile once, computes tile-local marginals IN-BLOCK,
//     recombines all lookups + relu + pooled dot. K6 finishes.
// No contended atomics; 5 launches.

#define NB 4
#define NN 24
#define ND 16
#define NS 16
#define NO 16
#define NKL 576

typedef unsigned int u32;
typedef unsigned short u16;

__device__ __forceinline__ u16 f2bf(float f) {
  u32 u = __float_as_uint(f);
  u = (u + 0x7fffu + ((u >> 16) & 1u)) >> 16;  // RNE
  return (u16)u;
}
__device__ __forceinline__ float bflo(u32 u) { return __uint_as_float(u << 16); }
__device__ __forceinline__ float bfhi(u32 u) { return __uint_as_float(u & 0xffff0000u); }

// ---------------- KB: eval (R8-proven code shape) ----------------------------
// thread: grp=t>>3 (=l), sub=t&7, elements k = 3*sub + c, c=0..2.
__global__ __launch_bounds__(192, 2) void kb_eval(
    const int* __restrict__ xcat, const float* __restrict__ xfeat,
    const float* __restrict__ embed,
    const float* __restrict__ coefs1, const float* __restrict__ bias1,
    u32* __restrict__ T1g) {
  const int blk = blockIdx.x;  // (b*24+i)*24+j
  const int j = blk % NN, i = (blk / NN) % NN, b = blk / (NN * NN);
  const int t = threadIdx.x;
  __shared__ float sx[NN * ND];
  __shared__ float SwL[16];
  __shared__ float Af[256], tb[256], tg[256], td[256];
  __shared__ float dconst[16];
  __shared__ __align__(16) float tabL[1152];  // A-pack | Bt | Gt2

  for (int idx = t; idx < NN * ND; idx += 192) {
    int d = idx & 15, ii = idx >> 4;
    float v;
    if (d < 15) v = fmaxf(embed[xcat[b * NN + ii] * 15 + d], 0.f);
    else        v = xfeat[b * NN + ii];
    sx[idx] = v;
  }
  __syncthreads();
  if (t < 16) {
    float s = 0.f;
    for (int ii = 0; ii < NN; ++ii) s += sx[ii * 16 + t];
    SwL[t] = s;
  }
  __syncthreads();
  for (int idx = t; idx < 256; idx += 192) {  // idx = d*16+s
    int d = idx >> 4, s = idx & 15;
    const float* c = coefs1 + idx * 16;
    float xi = sx[i * 16 + d], xj = sx[j * 16 + d];
    float Sv = SwL[d];
    float S2 = Sv * Sv, S3 = S2 * Sv, S4 = S2 * S2, pij = xi * xj;
    Af[s * 16 + d] = c[0] * pij + c[1] * Sv * xj + c[2] * Sv * xi + c[5] * S2;
    tb[idx] = c[4] * Sv * pij + c[9] * S2 * xi + c[7] * S2 * xj + c[12] * S3;
    tg[idx] = c[3] * Sv * pij + c[8] * S2 * xi + c[6] * S2 * xj + c[11] * S3;
    td[idx] = c[10] * S2 * pij + c[14] * S3 * xi + c[13] * S3 * xj + c[15] * S4;
  }
  __syncthreads();
  if (t < 16) {
    float sd = 0.f;
    for (int d = 0; d < 16; ++d) sd += td[d * 16 + t];
    dconst[t] = sd + bias1[t];
  }
  __syncthreads();
  if (t < 128) {  // A bf16-pack from Af: s=t>>3, m=t&7
    int s = t >> 3, m = t & 7;
    tabL[t] = __uint_as_float((u32)f2bf(Af[s * 16 + 2 * m]) |
                              ((u32)f2bf(Af[s * 16 + 2 * m + 1]) << 16));
  }
  for (int idx = t; idx < 768; idx += 192) {
    int pos = idx >> 4, s = idx & 15;
    if (pos < NN) {
      float acc = 0.f;
#pragma unroll
      for (int d = 0; d < 16; ++d) acc += tb[d * 16 + s] * sx[pos * 16 + d];
      tabL[128 + s * 32 + (pos / 3) * 4 + pos % 3] = acc;
    } else {
      int l = pos - NN;
      float acc = dconst[s];
#pragma unroll
      for (int d = 0; d < 16; ++d) acc += tg[d * 16 + s] * sx[l * 16 + d];
      tabL[640 + s * 32 + (l / 3) * 4 + l % 3] = acc;
    }
  }
  __syncthreads();

  const int grp = t >> 3, sub = t & 7, vr = 3 * sub;
  const int grpPos = (grp / 3) * 4 + grp % 3;
  float P0[16], P1[16], P2[16];
#pragma unroll
  for (int d = 0; d < 16; ++d) {
    float xc = sx[grp * 16 + d];
    P0[d] = sx[vr * 16 + d] * xc;
    P1[d] = sx[(vr + 1) * 16 + d] * xc;
    P2[d] = sx[(vr + 2) * 16 + d] * xc;
  }
  float pr0[16], pr1[16], pr2[16];
#pragma unroll
  for (int s = 0; s < 16; ++s) {
    const uint4* ap = (const uint4*)(tabL + s * 8);
    uint4 A0 = ap[0], A1 = ap[1];
    u32 qa[8] = {A0.x, A0.y, A0.z, A0.w, A1.x, A1.y, A1.z, A1.w};
    float Afr[16];
#pragma unroll
    for (int m = 0; m < 8; ++m) {
      Afr[2 * m] = bflo(qa[m]);
      Afr[2 * m + 1] = bfhi(qa[m]);
    }
    float4 vb4 = *(const float4*)(tabL + 128 + s * 32 + sub * 4);
    float ct = tabL[640 + s * 32 + grpPos];
    float v0 = vb4.x + ct, v1 = vb4.y + ct, v2 = vb4.z + ct;
#pragma unroll
    for (int d = 0; d < 16; ++d) {
      v0 += Afr[d] * P0[d];
      v1 += Afr[d] * P1[d];
      v2 += Afr[d] * P2[d];
    }
    pr0[s] = fmaxf(v0, 0.f);
    pr1[s] = fmaxf(v1, 0.f);
    pr2[s] = fmaxf(v2, 0.f);
  }
  const int klA = vr * NN + grp;
  auto emit = [&](float (&pr)[16], int kl) {
    u32 w[8];
#pragma unroll
    for (int m = 0; m < 8; ++m)
      w[m] = (u32)f2bf(pr[2 * m]) | ((u32)f2bf(pr[2 * m + 1]) << 16);
    uint4* gp = (uint4*)(T1g + ((size_t)blk * NKL + kl) * 8);
    gp[0] = make_uint4(w[0], w[1], w[2], w[3]);
    gp[1] = make_uint4(w[4], w[5], w[6], w[7]);
  };
  emit(pr0, klA); emit(pr1, klA + NN); emit(pr2, klA + 2 * NN);
}

// ---------------- K3: marginals, 4 threads/position (latency split) ---------
// g = bb*256+t; p = g>>2 position, quarter = g&3 sums 6 of 24 terms.
// shfl-xor(1,2) combine -> all 4 lanes hold full sum; quarter0 stores raw,
// quarter1 contracts+stores; quad via xor-butterfly (offsets 4..32 = exact).
__global__ __launch_bounds__(256) void k3_marg(
    const u32* __restrict__ T1g, const float* __restrict__ coefs2,
    u32* __restrict__ mi_p, u32* __restrict__ mj_p,
    u32* __restrict__ mic_p, u32* __restrict__ mjc_p,
    float* __restrict__ quad_part) {
  const int t = threadIdx.x, bb = blockIdx.x;
  const bool isI = bb < 864;          // block-uniform (1728 blocks total)
  const int g = bb * 256 + t;
  const int gg = isI ? g : g - 221184;
  const int p = gg >> 2, quarter = gg & 3;
  __shared__ __align__(16) float ccT[16][20];  // [s2][s]
  __shared__ float qred[4][16];
  {
    int s = t >> 4, s2 = t & 15;
    ccT[s2][s] = coefs2[t * 16 + (isI ? 1 : 2)];
  }
  __syncthreads();
  const int ba = p / NKL, kl = p % NKL;
  const int b = ba / NN, a = ba % NN;
  const u32* base; size_t stride;
  if (isI) { base = T1g + ((size_t)(b * NN * NN + a) * NKL + kl) * 8; stride = (size_t)NN * NKL * 8; }
  else     { base = T1g + ((size_t)((b * NN + a) * NN) * NKL + kl) * 8; stride = (size_t)NKL * 8; }
  const u32* qbase = base + (size_t)quarter * 6 * stride;
  float raw[16];
#pragma unroll
  for (int s = 0; s < 16; ++s) raw[s] = 0.f;
#pragma unroll
  for (int it = 0; it < 6; ++it) {
    const uint4* q = (const uint4*)(qbase + it * stride);
    uint4 q0 = q[0], q1 = q[1];
    u32 qa[8] = {q0.x, q0.y, q0.z, q0.w, q1.x, q1.y, q1.z, q1.w};
#pragma unroll
    for (int m = 0; m < 8; ++m) {
      raw[2 * m] += bflo(qa[m]);
      raw[2 * m + 1] += bfhi(qa[m]);
    }
  }
  // combine quarters (lanes xor 1, 2 share the same position)
#pragma unroll
  for (int s = 0; s < 16; ++s) {
    float v = raw[s];
    v += __shfl_xor(v, 1, 64);
    v += __shfl_xor(v, 2, 64);
    raw[s] = v;
  }
  if (quarter == 0) {  // store packed raw marginal
    u32 rp[8];
#pragma unroll
    for (int m = 0; m < 8; ++m)
      rp[m] = (u32)f2bf(raw[2 * m]) | ((u32)f2bf(raw[2 * m + 1]) << 16);
    uint4* rdst = (uint4*)((isI ? mi_p : mj_p) + (size_t)p * 8);
    rdst[0] = make_uint4(rp[0], rp[1], rp[2], rp[3]);
    rdst[1] = make_uint4(rp[4], rp[5], rp[6], rp[7]);
  } else if (quarter == 1) {  // contract + store
    u32 op[8];
#pragma unroll
    for (int m = 0; m < 8; ++m) {
      float o0 = 0.f, o1 = 0.f;
#pragma unroll
      for (int w = 0; w < 4; ++w) {
        float4 m0 = ((const float4*)(&ccT[2 * m][0]))[w];
        float4 m1 = ((const float4*)(&ccT[2 * m + 1][0]))[w];
        o0 += m0.x * raw[4 * w] + m0.y * raw[4 * w + 1] + m0.z * raw[4 * w + 2] + m0.w * raw[4 * w + 3];
        o1 += m1.x * raw[4 * w] + m1.y * raw[4 * w + 1] + m1.z * raw[4 * w + 2] + m1.w * raw[4 * w + 3];
      }
      op[m] = (u32)f2bf(o0) | ((u32)f2bf(o1) << 16);
    }
    uint4* cdst = (uint4*)((isI ? mic_p : mjc_p) + (size_t)p * 8);
    cdst[0] = make_uint4(op[0], op[1], op[2], op[3]);
    cdst[1] = make_uint4(op[4], op[5], op[6], op[7]);
  }
  if (isI) {
    // xor-butterfly over quads: each lane ends with the exact sum of the
    // wave's 16 positions (within-quad lanes hold identical values)
#pragma unroll
    for (int s = 0; s < 16; ++s) {
      float v = raw[s];
      v += __shfl_xor(v, 4, 64);
      v += __shfl_xor(v, 8, 64);
      v += __shfl_xor(v, 16, 64);
      v += __shfl_xor(v, 32, 64);
      raw[s] = v;
    }
    if ((t & 63) == 0) {
      int w = t >> 6;
#pragma unroll
      for (int s = 0; s < 16; ++s) qred[w][s] = raw[s];
    }
  }
  __syncthreads();
  if (isI && t < 16)
    quad_part[bb * 16 + t] = qred[0][t] + qred[1][t] + qred[2][t] + qred[3][t];
}

// ---------------- KD: pairs (360) + triples (384) + quad finisher (1) -------
__global__ __launch_bounds__(256) void kd_derived(
    const u32* __restrict__ mi_p, const u32* __restrict__ mj_p,
    const float* __restrict__ quad_part, const float* __restrict__ coefs2,
    float* __restrict__ mijc, float* __restrict__ mikc, float* __restrict__ milc,
    float* __restrict__ mjkc, float* __restrict__ mjlc,
    float* __restrict__ mijkc, float* __restrict__ mijlc,
    float* __restrict__ miklc, float* __restrict__ mjklc,
    float* __restrict__ mijklc) {
  const int bb = blockIdx.x, t = threadIdx.x;
  __shared__ float cc[256];
  __shared__ float ex[32][17];
  __shared__ float tot[16];
  __shared__ float qr[64];
  if (bb < 360) {  // pairs: 5 tables x 72 blocks; thread = (pp<32, m<8)
    int tbl = bb / 72;
    cc[t] = coefs2[t * 16 + 5 + tbl];
    int pp = t >> 3, m = t & 7;
    int pos = (bb % 72) * 32 + pp;
    int b = pos / 576, rem = pos % 576;
    const u32* srcb; int stride;
    if (tbl == 0) { srcb = mi_p + ((size_t)b * 24 * 576 + rem) * 8 + m; stride = 576 * 8; }
    else if (tbl == 1) { int jj = rem / 24, l = rem % 24;
      srcb = mi_p + (((size_t)(b * 24 + jj)) * 576 + l) * 8 + m; stride = 24 * 8; }
    else if (tbl == 2) { int jj = rem / 24, k = rem % 24;
      srcb = mi_p + (((size_t)(b * 24 + jj)) * 576 + k * 24) * 8 + m; stride = 8; }
    else if (tbl == 3) { int ii = rem / 24, l = rem % 24;
      srcb = mj_p + (((size_t)(b * 24 + ii)) * 576 + l) * 8 + m; stride = 24 * 8; }
    else { int ii = rem / 24, k = rem % 24;
      srcb = mj_p + (((size_t)(b * 24 + ii)) * 576 + k * 24) * 8 + m; stride = 8; }
    float v0 = 0.f, v1 = 0.f;
#pragma unroll 4
    for (int x = 0; x < 24; ++x) {
      u32 u = srcb[(size_t)x * stride];
      v0 += bflo(u); v1 += bfhi(u);
    }
    ex[pp][2 * m] = v0;
    ex[pp][2 * m + 1] = v1;
    __syncthreads();
    float* dst = (tbl == 0 ? mijc : tbl == 1 ? mikc : tbl == 2 ? milc : tbl == 3 ? mjkc : mjlc);
    for (int idx = t; idx < 512; idx += 256) {
      int pp2 = idx >> 4, s2 = idx & 15;
      float o = 0.f;
#pragma unroll
      for (int ss = 0; ss < 16; ++ss) o += cc[ss * 16 + s2] * ex[pp2][ss];
      dst[(size_t)((bb % 72) * 32 + pp2) * 16 + s2] = o;
    }
    return;
  }
  if (bb < 360 + 384) {  // triples: thread = (gg<32, m<8), 18 iters
    int idx = bb - 360;
    int tbl = idx / 96, rr = idx % 96;
    int b = rr / 24, a = rr % 24;
    cc[t] = coefs2[t * 16 + 11 + tbl];
    int gg = t >> 3, m = t & 7;
    const u32* src = (tbl == 3 ? mj_p : mi_p);
    float v0 = 0.f, v1 = 0.f;
#pragma unroll 2
    for (int it = 0; it < 18; ++it) {
      int u = gg + (it << 5);
      size_t addr;
      if (tbl == 0) { int j = u / 24, k = u % 24;
        addr = (((size_t)(b * 24 + j)) * 576 + k * 24 + a) * 8 + m; }
      else if (tbl == 1) { int j = u / 24, l = u % 24;
        addr = (((size_t)(b * 24 + j)) * 576 + a * 24 + l) * 8 + m; }
      else {
        addr = (((size_t)(b * 24 + a)) * 576 + u) * 8 + m; }
      u32 uu = src[addr];
      v0 += bflo(uu); v1 += bfhi(uu);
    }
    ex[gg][2 * m] = v0;
    ex[gg][2 * m + 1] = v1;
    __syncthreads();
    if (t < 16) {
      float w2 = 0.f;
#pragma unroll
      for (int g2 = 0; g2 < 32; ++g2) w2 += ex[g2][t];
      tot[t] = w2;
    }
    __syncthreads();
    if (t < 16) {
      float o = 0.f;
#pragma unroll
      for (int ss = 0; ss < 16; ++ss) o += cc[ss * 16 + t] * tot[ss];
      float* dst = (tbl == 0 ? mijkc : tbl == 1 ? mijlc : tbl == 2 ? miklc : mjklc);
      dst[(size_t)(b * 24 + a) * 16 + t] = o;
    }
    return;
  }
  // quad finisher: 216 block-partials per b
  if (t < 64) {
    int b = t >> 4, s = t & 15;
    float v = 0.f;
    for (int c = 0; c < 216; ++c) v += quad_part[(b * 216 + c) * 16 + s];
    qr[t] = v;
  }
  __syncthreads();
  if (t < 64) {
    int b = t >> 4, s2 = t & 15;
    float o = 0.f;
#pragma unroll
    for (int s = 0; s < 16; ++s) o += coefs2[(s * 16 + s2) * 16 + 15] * qr[b * 16 + s];
    mijklc[t] = o;
  }
}

// ---------------- K5: tile load + in-block local marginals + layer2 + pool --
__global__ __launch_bounds__(192, 2) void k5_final(
    const u32* __restrict__ T1g,
    const u32* __restrict__ mic_p, const u32* __restrict__ mjc_p,
    const float* __restrict__ mijc, const float* __restrict__ mikc,
    const float* __restrict__ milc, const float* __restrict__ mjkc,
    const float* __restrict__ mjlc,
    const float* __restrict__ mijkc, const float* __restrict__ mijlc,
    const float* __restrict__ miklc, const float* __restrict__ mjklc,
    const float* __restrict__ mijklc,
    const float* __restrict__ coefs2, const float* __restrict__ bias2,
    const float* __restrict__ w_out, float* __restrict__ pool_part) {
  const int orig = blockIdx.x;
  const int blk = (orig & 7) * 288 + (orig >> 3);  // XCD swizzle
  const int j = blk % NN, i2 = (blk / NN) % NN, b = blk / (NN * NN);
  const int t = threadIdx.x;
  __shared__ __align__(16) u32 c2p[128];
  __shared__ __align__(16) float c2kT[16][20], c2lT[16][20], c2qT[16][20];
  __shared__ u32 T1p[NKL][9];
  __shared__ __align__(16) float rk[NN][20], rl[NN][20];
  __shared__ __align__(16) float rkl[16];
  __shared__ __align__(16) float Kt[NN][16], Lt[NN][16];
  __shared__ __align__(16) float cterm[16], wl[16];
  __shared__ float wsum[3];

  u32 qa0[8], qa1[8], qa2[8];
  auto loadT = [&](int c, u32 (&qa)[8]) {
    const int kl = t + 192 * c;
    const uint4* pt = (const uint4*)(T1g + ((size_t)blk * NKL + kl) * 8);
    uint4 t0 = pt[0], t1 = pt[1];
    qa[0] = t0.x; qa[1] = t0.y; qa[2] = t0.z; qa[3] = t0.w;
    qa[4] = t1.x; qa[5] = t1.y; qa[6] = t1.z; qa[7] = t1.w;
#pragma unroll
    for (int m = 0; m < 8; ++m) T1p[kl][m] = qa[m];
  };
  loadT(0, qa0); loadT(1, qa1); loadT(2, qa2);
  if (t < 128) {
    int s = t >> 3, m = t & 7;
    c2p[t] = (u32)f2bf(coefs2[(s * 16 + 2 * m) * 16]) |
             ((u32)f2bf(coefs2[(s * 16 + 2 * m + 1) * 16]) << 16);
  }
  for (int idx = t; idx < 256; idx += 192) {
    int s = idx >> 4, s2 = idx & 15;
    c2kT[s2][s] = coefs2[idx * 16 + 3];
    c2lT[s2][s] = coefs2[idx * 16 + 4];
    c2qT[s2][s] = coefs2[idx * 16 + 10];
  }
  __syncthreads();

  for (int idx = t; idx < NN * NS; idx += 192) {
    int a = idx >> 4, s = idx & 15, m = s >> 1;
    u32 odd = (u32)(s & 1);
    float sk = 0.f, sl = 0.f;
    for (int c = 0; c < NN; ++c) {
      u32 uk = T1p[c * NN + a][m];
      u32 ul = T1p[a * NN + c][m];
      sk += odd ? bfhi(uk) : bflo(uk);
      sl += odd ? bfhi(ul) : bflo(ul);
    }
    rk[a][s] = sk;
    rl[a][s] = sl;
  }
  __syncthreads();
  if (t < 16) {
    float v = 0.f;
    for (int a = 0; a < NN; ++a) v += rk[a][t];
    rkl[t] = v;
  }
  __syncthreads();
  for (int idx = t; idx < NN * NO; idx += 192) {
    int kk = idx >> 4, s2 = idx & 15;
    const float4* ck = (const float4*)(&c2kT[s2][0]);
    const float4* cl = (const float4*)(&c2lT[s2][0]);
    const float4* rkr = (const float4*)(&rk[kk][0]);
    const float4* rlr = (const float4*)(&rl[kk][0]);
    float ok = 0.f, ol = 0.f;
#pragma unroll
    for (int w = 0; w < 4; ++w) {
      float4 mk4 = ck[w], ml4 = cl[w], rk4 = rkr[w], rl4 = rlr[w];
      ok += mk4.x * rk4.x + mk4.y * rk4.y + mk4.z * rk4.z + mk4.w * rk4.w;
      ol += ml4.x * rl4.x + ml4.y * rl4.y + ml4.z * rl4.z + ml4.w * rl4.w;
    }
    Lt[kk][s2] = ok
               + mjkc[(size_t)((b * NN + i2) * NN + kk) * NS + s2]
               + mikc[(size_t)((b * NN + j) * NN + kk) * NS + s2]
               + mijkc[(size_t)(b * NN + kk) * NS + s2];
    Kt[kk][s2] = ol
               + mjlc[(size_t)((b * NN + i2) * NN + kk) * NS + s2]
               + milc[(size_t)((b * NN + j) * NN + kk) * NS + s2]
               + mijlc[(size_t)(b * NN + kk) * NS + s2];
  }
  if (t < NO) {
    float oq = 0.f;
#pragma unroll
    for (int s = 0; s < 16; ++s) oq += c2qT[t][s] * rkl[s];
    cterm[t] = oq
             + miklc[(size_t)(b * NN + j) * NS + t]
             + mjklc[(size_t)(b * NN + i2) * NS + t]
             + mijklc[(size_t)b * NS + t] + bias2[t];
    wl[t] = w_out[t];
  }
  __syncthreads();

  float acc0[16], acc1[16], acc2[16];
  auto initElem = [&](int c, u32 (&qa)[8], float (&acc)[16]) {
    const int kl = t + 192 * c;
    const int k = kl / NN, l = kl % NN;
    const uint4* pi = (const uint4*)(mic_p + ((size_t)((b * NN + j) * NKL + kl)) * 8);
    const uint4* pj = (const uint4*)(mjc_p + ((size_t)((b * NN + i2) * NKL + kl)) * 8);
    const float4* ps = (const float4*)(mijc + ((size_t)(b * NKL + kl)) * 16);
    uint4 i0 = pi[0], i1 = pi[1];
    uint4 j0 = pj[0], j1 = pj[1];
    float4 s0 = ps[0], s1 = ps[1], s2v = ps[2], s3 = ps[3];
    u32 ia[8] = {i0.x, i0.y, i0.z, i0.w, i1.x, i1.y, i1.z, i1.w};
    u32 ja[8] = {j0.x, j0.y, j0.z, j0.w, j1.x, j1.y, j1.z, j1.w};
    float sv[16];
    ((float4*)sv)[0] = s0; ((float4*)sv)[1] = s1; ((float4*)sv)[2] = s2v; ((float4*)sv)[3] = s3;
#pragma unroll
    for (int m = 0; m < 8; ++m) {
      acc[2 * m]     = cterm[2 * m]     + Kt[k][2 * m]     + Lt[l][2 * m]
                     + bflo(ia[m]) + bflo(ja[m]) + sv[2 * m];
      acc[2 * m + 1] = cterm[2 * m + 1] + Kt[k][2 * m + 1] + Lt[l][2 * m + 1]
                     + bfhi(ia[m]) + bfhi(ja[m]) + sv[2 * m + 1];
    }
  };
  initElem(0, qa0, acc0); initElem(1, qa1, acc1); initElem(2, qa2, acc2);

#pragma unroll
  for (int s = 0; s < 16; ++s) {
    const uint4* cp = (const uint4*)(c2p + s * 8);
    uint4 C0 = cp[0], C1 = cp[1];
    u32 ca[8] = {C0.x, C0.y, C0.z, C0.w, C1.x, C1.y, C1.z, C1.w};
    float row[16];
#pragma unroll
    for (int m = 0; m < 8; ++m) {
      row[2 * m] = bflo(ca[m]);
      row[2 * m + 1] = bfhi(ca[m]);
    }
    float v0 = (s & 1) ? bfhi(qa0[s >> 1]) : bflo(qa0[s >> 1]);
    float v1 = (s & 1) ? bfhi(qa1[s >> 1]) : bflo(qa1[s >> 1]);
    float v2 = (s & 1) ? bfhi(qa2[s >> 1]) : bflo(qa2[s >> 1]);
#pragma unroll
    for (int s2 = 0; s2 < 16; ++s2) {
      acc0[s2] += row[s2] * v0;
      acc1[s2] += row[s2] * v1;
      acc2[s2] += row[s2] * v2;
    }
  }
  float p = 0.f;
#pragma unroll
  for (int s2 = 0; s2 < 16; ++s2)
    p += wl[s2] * (fmaxf(acc0[s2], 0.f) + fmaxf(acc1[s2], 0.f) + fmaxf(acc2[s2], 0.f));
  for (int off = 32; off; off >>= 1) p += __shfl_down(p, off, 64);
  if ((t & 63) == 0) wsum[t >> 6] = p;
  __syncthreads();
  if (t == 0) pool_part[blk] = wsum[0] + wsum[1] + wsum[2];
}

// ---------------- K6: pooled partials -> out --------------------------------
__global__ __launch_bounds__(256) void k6_out(
    const float* __restrict__ pool_part, const float* __restrict__ b_out,
    float* __restrict__ out) {
  const int t = threadIdx.x;
  const int b = t >> 6, lane = t & 63;
  float v = 0.f;
  for (int c = lane; c < 576; c += 64) v += pool_part[b * 576 + c];
  for (int off = 32; off; off >>= 1) v += __shfl_down(v, off, 64);
  if (lane == 0) out[b] = v + b_out[0];
}

// ---------------- launch -----------------------------------------------------
extern "C" void kernel_launch(void* const* d_in, const int* in_sizes, int n_in,
                              void* d_out, int out_size, void* d_ws, size_t ws_size,
                              hipStream_t stream) {
  (void)in_sizes; (void)n_in; (void)out_size; (void)ws_size;
  const int*   xcat   = (const int*)d_in[0];
  const float* xfeat  = (const float*)d_in[1];
  const float* embed  = (const float*)d_in[2];
  const float* coefs1 = (const float*)d_in[3];
  const float* bias1  = (const float*)d_in[4];
  const float* coefs2 = (const float*)d_in[5];
  const float* bias2  = (const float*)d_in[6];
  const float* w_out  = (const float*)d_in[7];
  const float* b_out  = (const float*)d_in[8];
  float* out = (float*)d_out;
  char* ws = (char*)d_ws;

  u32*   T1g      = (u32*)(ws + 0);            // 42,467,328 B
  u32*   mi_p     = (u32*)(ws + 42467328);     // 1,769,472 B each
  u32*   mj_p     = (u32*)(ws + 44236800);
  u32*   mic_p    = (u32*)(ws + 46006272);
  u32*   mjc_p    = (u32*)(ws + 47775744);
  float* mijc     = (float*)(ws + 49545216);   // 147,456 B x5
  float* mikc     = (float*)(ws + 49692672);
  float* milc     = (float*)(ws + 49840128);
  float* mjkc     = (float*)(ws + 49987584);
  float* mjlc     = (float*)(ws + 50135040);
  float* mijkc    = (float*)(ws + 50282496);   // 6,144 B x4
  float* mijlc    = (float*)(ws + 50288640);
  float* miklc    = (float*)(ws + 50294784);
  float* mjklc    = (float*)(ws + 50300928);
  float* mijklc   = (float*)(ws + 50307072);   // 256 B
  float* quad_part= (float*)(ws + 50307328);   // 55,296 B (864 blk x 16)
  float* pool_part= (float*)(ws + 50362624);   // 9,216 B

  kb_eval<<<NB * NN * NN, 192, 0, stream>>>(xcat, xfeat, embed, coefs1, bias1, T1g);
  k3_marg<<<1728, 256, 0, stream>>>(T1g, coefs2, mi_p, mj_p, mic_p, mjc_p, quad_part);
  kd_derived<<<745, 256, 0, stream>>>(mi_p, mj_p, quad_part, coefs2,
                                      mijc, mikc, milc, mjkc, mjlc,
                                      mijkc, mijlc, miklc, mjklc, mijklc);
  k5_final<<<NB * NN * NN, 192, 0, stream>>>(T1g, mic_p, mjc_p,
                                             mijc, mikc, milc, mjkc, mjlc,
                                             mijkc, mijlc, miklc, mjklc, mijklc,
                                             coefs2, bias2, w_out, pool_part);
  k6_out<<<1, 256, 0, stream>>>(pool_part, b_out, out);
}

// Round 12
// 98.839 us; speedup vs baseline: 1.0740x; 1.0740x over previous
//
#include <hip/hip_runtime.h>
#include <hip/hip_bf16.h>

// Eq4Net: permutation-equivariant 4th-order set network.
// T = x^{ox4} is rank-1 per channel: layer-1 pre-activations are
//   pre[s](k,l) = sum_d A_ij[s][d]*x_k[d]*x_l[d] + Bt_ij[k][s] + Gt2_ij[l][s].
// KB: per-tile eval (tables in LDS); thread owns kl = t,t+192,t+384 (shared l,
//     k = t/24+{0,8,16}; Bt padded [s*32+(k%8)*4+k/8]) -> COALESCED T1 stores.
// K3: streams T1 twice for i/j marginals (raw + contracted, bf16-packed).
// KD: pair/triple/quad tables from packed marginals.
// K5: loads its tile once, computes tile-local marginals IN-BLOCK,
//     recombines all lookups + relu + pooled dot. K6 finishes.
// No contended atomics; 5 launches.

#define NB 4
#define NN 24
#define ND 16
#define NS 16
#define NO 16
#define NKL 576

typedef unsigned int u32;
typedef unsigned short u16;

__device__ __forceinline__ u16 f2bf(float f) {
  u32 u = __float_as_uint(f);
  u = (u + 0x7fffu + ((u >> 16) & 1u)) >> 16;  // RNE
  return (u16)u;
}
__device__ __forceinline__ float bflo(u32 u) { return __uint_as_float(u << 16); }
__device__ __forceinline__ float bfhi(u32 u) { return __uint_as_float(u & 0xffff0000u); }

// ---------------- KB: eval, coalesced T1 stores ------------------------------
// thread: l = t%24 (shared), k = t/24 + {0,8,16} -> kl = t, t+192, t+384.
__global__ __launch_bounds__(192, 2) void kb_eval(
    const int* __restrict__ xcat, const float* __restrict__ xfeat,
    const float* __restrict__ embed,
    const float* __restrict__ coefs1, const float* __restrict__ bias1,
    u32* __restrict__ T1g) {
  const int blk = blockIdx.x;  // (b*24+i)*24+j
  const int j = blk % NN, i = (blk / NN) % NN, b = blk / (NN * NN);
  const int t = threadIdx.x;
  __shared__ float sx[NN * ND];
  __shared__ float SwL[16];
  __shared__ float Af[256], tb[256], tg[256], td[256];
  __shared__ float dconst[16];
  __shared__ __align__(16) float tabL[1152];  // A-pack | Bt | Gt2

  for (int idx = t; idx < NN * ND; idx += 192) {
    int d = idx & 15, ii = idx >> 4;
    float v;
    if (d < 15) v = fmaxf(embed[xcat[b * NN + ii] * 15 + d], 0.f);
    else        v = xfeat[b * NN + ii];
    sx[idx] = v;
  }
  __syncthreads();
  if (t < 16) {
    float s = 0.f;
    for (int ii = 0; ii < NN; ++ii) s += sx[ii * 16 + t];
    SwL[t] = s;
  }
  __syncthreads();
  for (int idx = t; idx < 256; idx += 192) {  // idx = d*16+s
    int d = idx >> 4, s = idx & 15;
    const float* c = coefs1 + idx * 16;
    float xi = sx[i * 16 + d], xj = sx[j * 16 + d];
    float Sv = SwL[d];
    float S2 = Sv * Sv, S3 = S2 * Sv, S4 = S2 * S2, pij = xi * xj;
    Af[s * 16 + d] = c[0] * pij + c[1] * Sv * xj + c[2] * Sv * xi + c[5] * S2;
    tb[idx] = c[4] * Sv * pij + c[9] * S2 * xi + c[7] * S2 * xj + c[12] * S3;
    tg[idx] = c[3] * Sv * pij + c[8] * S2 * xi + c[6] * S2 * xj + c[11] * S3;
    td[idx] = c[10] * S2 * pij + c[14] * S3 * xi + c[13] * S3 * xj + c[15] * S4;
  }
  __syncthreads();
  if (t < 16) {
    float sd = 0.f;
    for (int d = 0; d < 16; ++d) sd += td[d * 16 + t];
    dconst[t] = sd + bias1[t];
  }
  __syncthreads();
  if (t < 128) {  // A bf16-pack from Af: s=t>>3, m=t&7
    int s = t >> 3, m = t & 7;
    tabL[t] = __uint_as_float((u32)f2bf(Af[s * 16 + 2 * m]) |
                              ((u32)f2bf(Af[s * 16 + 2 * m + 1]) << 16));
  }
  for (int idx = t; idx < 768; idx += 192) {
    int pos = idx >> 4, s = idx & 15;
    if (pos < NN) {  // Bt[k] -> [s*32 + (k%8)*4 + k/8]  (k0-grouped float4)
      float acc = 0.f;
#pragma unroll
      for (int d = 0; d < 16; ++d) acc += tb[d * 16 + s] * sx[pos * 16 + d];
      tabL[128 + s * 32 + (pos % 8) * 4 + pos / 8] = acc;
    } else {         // Gt2[l] (+dconst) -> [s*32 + (l/3)*4 + l%3]
      int l = pos - NN;
      float acc = dconst[s];
#pragma unroll
      for (int d = 0; d < 16; ++d) acc += tg[d * 16 + s] * sx[l * 16 + d];
      tabL[640 + s * 32 + (l / 3) * 4 + l % 3] = acc;
    }
  }
  __syncthreads();

  const int l = t % NN, k0 = t / NN;  // elements k = k0, k0+8, k0+16
  const int lpos = (l / 3) * 4 + l % 3;
  float P0[16], P1[16], P2[16];
#pragma unroll
  for (int d = 0; d < 16; ++d) {
    float xl = sx[l * 16 + d];
    P0[d] = sx[k0 * 16 + d] * xl;
    P1[d] = sx[(k0 + 8) * 16 + d] * xl;
    P2[d] = sx[(k0 + 16) * 16 + d] * xl;
  }
  float pr0[16], pr1[16], pr2[16];
#pragma unroll
  for (int s = 0; s < 16; ++s) {
    const uint4* ap = (const uint4*)(tabL + s * 8);
    uint4 A0 = ap[0], A1 = ap[1];
    u32 qa[8] = {A0.x, A0.y, A0.z, A0.w, A1.x, A1.y, A1.z, A1.w};
    float Afr[16];
#pragma unroll
    for (int m = 0; m < 8; ++m) {
      Afr[2 * m] = bflo(qa[m]);
      Afr[2 * m + 1] = bfhi(qa[m]);
    }
    float4 vb4 = *(const float4*)(tabL + 128 + s * 32 + k0 * 4);
    float ct = tabL[640 + s * 32 + lpos];
    float v0 = vb4.x + ct, v1 = vb4.y + ct, v2 = vb4.z + ct;
#pragma unroll
    for (int d = 0; d < 16; ++d) {
      v0 += Afr[d] * P0[d];
      v1 += Afr[d] * P1[d];
      v2 += Afr[d] * P2[d];
    }
    pr0[s] = fmaxf(v0, 0.f);
    pr1[s] = fmaxf(v1, 0.f);
    pr2[s] = fmaxf(v2, 0.f);
  }
  auto emit = [&](float (&pr)[16], int kl) {
    u32 w[8];
#pragma unroll
    for (int m = 0; m < 8; ++m)
      w[m] = (u32)f2bf(pr[2 * m]) | ((u32)f2bf(pr[2 * m + 1]) << 16);
    uint4* gp = (uint4*)(T1g + ((size_t)blk * NKL + kl) * 8);
    gp[0] = make_uint4(w[0], w[1], w[2], w[3]);
    gp[1] = make_uint4(w[4], w[5], w[6], w[7]);
  };
  emit(pr0, t); emit(pr1, t + 192); emit(pr2, t + 384);  // coalesced
}

// ---------------- K3: m_i/m_j from T1 -> packed raw + packed contracted -----
__global__ __launch_bounds__(256) void k3_marg(
    const u32* __restrict__ T1g, const float* __restrict__ coefs2,
    u32* __restrict__ mi_p, u32* __restrict__ mj_p,
    u32* __restrict__ mic_p, u32* __restrict__ mjc_p,
    float* __restrict__ quad_part) {
  const int t = threadIdx.x, bb = blockIdx.x;
  const int pos = bb * 256 + t;       // 110592 total
  const bool isI = pos < 55296;       // block-uniform (216 blocks isI)
  const int p = isI ? pos : pos - 55296;
  __shared__ __align__(16) float ccT[16][20];  // [s2][s]
  __shared__ float qred[4][16];
  {
    int s = t >> 4, s2 = t & 15;
    ccT[s2][s] = coefs2[t * 16 + (isI ? 1 : 2)];
  }
  __syncthreads();
  const int ba = p / NKL, kl = p % NKL;
  const int b = ba / NN, a = ba % NN;
  const u32* base; size_t stride;
  if (isI) { base = T1g + ((size_t)(b * NN * NN + a) * NKL + kl) * 8; stride = (size_t)NN * NKL * 8; }
  else     { base = T1g + ((size_t)((b * NN + a) * NN) * NKL + kl) * 8; stride = (size_t)NKL * 8; }
  float raw[16];
#pragma unroll
  for (int s = 0; s < 16; ++s) raw[s] = 0.f;
#pragma unroll 4
  for (int c = 0; c < NN; ++c) {
    const uint4* q = (const uint4*)(base + c * stride);
    uint4 q0 = q[0], q1 = q[1];
    u32 qa[8] = {q0.x, q0.y, q0.z, q0.w, q1.x, q1.y, q1.z, q1.w};
#pragma unroll
    for (int m = 0; m < 8; ++m) {
      raw[2 * m] += bflo(qa[m]);
      raw[2 * m + 1] += bfhi(qa[m]);
    }
  }
  u32 rp[8], op[8];
#pragma unroll
  for (int m = 0; m < 8; ++m) {
    rp[m] = (u32)f2bf(raw[2 * m]) | ((u32)f2bf(raw[2 * m + 1]) << 16);
    float o0 = 0.f, o1 = 0.f;
#pragma unroll
    for (int w = 0; w < 4; ++w) {
      float4 m0 = ((const float4*)(&ccT[2 * m][0]))[w];
      float4 m1 = ((const float4*)(&ccT[2 * m + 1][0]))[w];
      o0 += m0.x * raw[4 * w] + m0.y * raw[4 * w + 1] + m0.z * raw[4 * w + 2] + m0.w * raw[4 * w + 3];
      o1 += m1.x * raw[4 * w] + m1.y * raw[4 * w + 1] + m1.z * raw[4 * w + 2] + m1.w * raw[4 * w + 3];
    }
    op[m] = (u32)f2bf(o0) | ((u32)f2bf(o1) << 16);
  }
  uint4* rdst = (uint4*)((isI ? mi_p : mj_p) + (size_t)p * 8);
  rdst[0] = make_uint4(rp[0], rp[1], rp[2], rp[3]);
  rdst[1] = make_uint4(rp[4], rp[5], rp[6], rp[7]);
  uint4* cdst = (uint4*)((isI ? mic_p : mjc_p) + (size_t)p * 8);
  cdst[0] = make_uint4(op[0], op[1], op[2], op[3]);
  cdst[1] = make_uint4(op[4], op[5], op[6], op[7]);
  if (isI) {
#pragma unroll
    for (int s = 0; s < 16; ++s) {
      float v = raw[s];
      for (int off = 32; off; off >>= 1) v += __shfl_xor(v, off, 64);
      raw[s] = v;
    }
    if ((t & 63) == 0) {
      int w = t >> 6;
#pragma unroll
      for (int s = 0; s < 16; ++s) qred[w][s] = raw[s];
    }
  }
  __syncthreads();
  if (isI && t < 16)
    quad_part[bb * 16 + t] = qred[0][t] + qred[1][t] + qred[2][t] + qred[3][t];
}

// ---------------- KD: pairs (360) + triples (384) + quad finisher (1) -------
__global__ __launch_bounds__(256) void kd_derived(
    const u32* __restrict__ mi_p, const u32* __restrict__ mj_p,
    const float* __restrict__ quad_part, const float* __restrict__ coefs2,
    float* __restrict__ mijc, float* __restrict__ mikc, float* __restrict__ milc,
    float* __restrict__ mjkc, float* __restrict__ mjlc,
    float* __restrict__ mijkc, float* __restrict__ mijlc,
    float* __restrict__ miklc, float* __restrict__ mjklc,
    float* __restrict__ mijklc) {
  const int bb = blockIdx.x, t = threadIdx.x;
  __shared__ float cc[256];
  __shared__ float ex[32][17];
  __shared__ float tot[16];
  __shared__ float qr[64];
  if (bb < 360) {  // pairs: 5 tables x 72 blocks; thread = (pp<32, m<8)
    int tbl = bb / 72;
    cc[t] = coefs2[t * 16 + 5 + tbl];
    int pp = t >> 3, m = t & 7;
    int pos = (bb % 72) * 32 + pp;
    int b = pos / 576, rem = pos % 576;
    const u32* srcb; int stride;
    if (tbl == 0) { srcb = mi_p + ((size_t)b * 24 * 576 + rem) * 8 + m; stride = 576 * 8; }
    else if (tbl == 1) { int jj = rem / 24, l = rem % 24;
      srcb = mi_p + (((size_t)(b * 24 + jj)) * 576 + l) * 8 + m; stride = 24 * 8; }
    else if (tbl == 2) { int jj = rem / 24, k = rem % 24;
      srcb = mi_p + (((size_t)(b * 24 + jj)) * 576 + k * 24) * 8 + m; stride = 8; }
    else if (tbl == 3) { int ii = rem / 24, l = rem % 24;
      srcb = mj_p + (((size_t)(b * 24 + ii)) * 576 + l) * 8 + m; stride = 24 * 8; }
    else { int ii = rem / 24, k = rem % 24;
      srcb = mj_p + (((size_t)(b * 24 + ii)) * 576 + k * 24) * 8 + m; stride = 8; }
    float v0 = 0.f, v1 = 0.f;
#pragma unroll 4
    for (int x = 0; x < 24; ++x) {
      u32 u = srcb[(size_t)x * stride];
      v0 += bflo(u); v1 += bfhi(u);
    }
    ex[pp][2 * m] = v0;
    ex[pp][2 * m + 1] = v1;
    __syncthreads();
    float* dst = (tbl == 0 ? mijc : tbl == 1 ? mikc : tbl == 2 ? milc : tbl == 3 ? mjkc : mjlc);
    for (int idx = t; idx < 512; idx += 256) {
      int pp2 = idx >> 4, s2 = idx & 15;
      float o = 0.f;
#pragma unroll
      for (int ss = 0; ss < 16; ++ss) o += cc[ss * 16 + s2] * ex[pp2][ss];
      dst[(size_t)((bb % 72) * 32 + pp2) * 16 + s2] = o;
    }
    return;
  }
  if (bb < 360 + 384) {  // triples: thread = (gg<32, m<8), 18 iters
    int idx = bb - 360;
    int tbl = idx / 96, rr = idx % 96;
    int b = rr / 24, a = rr % 24;
    cc[t] = coefs2[t * 16 + 11 + tbl];
    int gg = t >> 3, m = t & 7;
    const u32* src = (tbl == 3 ? mj_p : mi_p);
    float v0 = 0.f, v1 = 0.f;
#pragma unroll 2
    for (int it = 0; it < 18; ++it) {
      int u = gg + (it << 5);
      size_t addr;
      if (tbl == 0) { int j = u / 24, k = u % 24;
        addr = (((size_t)(b * 24 + j)) * 576 + k * 24 + a) * 8 + m; }
      else if (tbl == 1) { int j = u / 24, l = u % 24;
        addr = (((size_t)(b * 24 + j)) * 576 + a * 24 + l) * 8 + m; }
      else {
        addr = (((size_t)(b * 24 + a)) * 576 + u) * 8 + m; }
      u32 uu = src[addr];
      v0 += bflo(uu); v1 += bfhi(uu);
    }
    ex[gg][2 * m] = v0;
    ex[gg][2 * m + 1] = v1;
    __syncthreads();
    if (t < 16) {
      float w2 = 0.f;
#pragma unroll
      for (int g2 = 0; g2 < 32; ++g2) w2 += ex[g2][t];
      tot[t] = w2;
    }
    __syncthreads();
    if (t < 16) {
      float o = 0.f;
#pragma unroll
      for (int ss = 0; ss < 16; ++ss) o += cc[ss * 16 + t] * tot[ss];
      float* dst = (tbl == 0 ? mijkc : tbl == 1 ? mijlc : tbl == 2 ? miklc : mjklc);
      dst[(size_t)(b * 24 + a) * 16 + t] = o;
    }
    return;
  }
  // quad finisher: 54 block-partials per b
  if (t < 64) {
    int b = t >> 4, s = t & 15;
    float v = 0.f;
    for (int c = 0; c < 54; ++c) v += quad_part[(b * 54 + c) * 16 + s];
    qr[t] = v;
  }
  __syncthreads();
  if (t < 64) {
    int b = t >> 4, s2 = t & 15;
    float o = 0.f;
#pragma unroll
    for (int s = 0; s < 16; ++s) o += coefs2[(s * 16 + s2) * 16 + 15] * qr[b * 16 + s];
    mijklc[t] = o;
  }
}

// ---------------- K5: tile load + in-block local marginals + layer2 + pool --
__global__ __launch_bounds__(192, 2) void k5_final(
    const u32* __restrict__ T1g,
    const u32* __restrict__ mic_p, const u32* __restrict__ mjc_p,
    const float* __restrict__ mijc, const float* __restrict__ mikc,
    const float* __restrict__ milc, const float* __restrict__ mjkc,
    const float* __restrict__ mjlc,
    const float* __restrict__ mijkc, const float* __restrict__ mijlc,
    const float* __restrict__ miklc, const float* __restrict__ mjklc,
    const float* __restrict__ mijklc,
    const float* __restrict__ coefs2, const float* __restrict__ bias2,
    const float* __restrict__ w_out, float* __restrict__ pool_part) {
  const int orig = blockIdx.x;
  const int blk = (orig & 7) * 288 + (orig >> 3);  // XCD swizzle
  const int j = blk % NN, i2 = (blk / NN) % NN, b = blk / (NN * NN);
  const int t = threadIdx.x;
  __shared__ __align__(16) u32 c2p[128];
  __shared__ __align__(16) float c2kT[16][20], c2lT[16][20], c2qT[16][20];
  __shared__ u32 T1p[NKL][9];
  __shared__ __align__(16) float rk[NN][20], rl[NN][20];
  __shared__ __align__(16) float rkl[16];
  __shared__ __align__(16) float Kt[NN][16], Lt[NN][16];
  __shared__ __align__(16) float cterm[16], wl[16];
  __shared__ float wsum[3];

  u32 qa0[8], qa1[8], qa2[8];
  auto loadT = [&](int c, u32 (&qa)[8]) {
    const int kl = t + 192 * c;
    const uint4* pt = (const uint4*)(T1g + ((size_t)blk * NKL + kl) * 8);
    uint4 t0 = pt[0], t1 = pt[1];
    qa[0] = t0.x; qa[1] = t0.y; qa[2] = t0.z; qa[3] = t0.w;
    qa[4] = t1.x; qa[5] = t1.y; qa[6] = t1.z; qa[7] = t1.w;
#pragma unroll
    for (int m = 0; m < 8; ++m) T1p[kl][m] = qa[m];
  };
  loadT(0, qa0); loadT(1, qa1); loadT(2, qa2);
  if (t < 128) {
    int s = t >> 3, m = t & 7;
    c2p[t] = (u32)f2bf(coefs2[(s * 16 + 2 * m) * 16]) |
             ((u32)f2bf(coefs2[(s * 16 + 2 * m + 1) * 16]) << 16);
  }
  for (int idx = t; idx < 256; idx += 192) {
    int s = idx >> 4, s2 = idx & 15;
    c2kT[s2][s] = coefs2[idx * 16 + 3];
    c2lT[s2][s] = coefs2[idx * 16 + 4];
    c2qT[s2][s] = coefs2[idx * 16 + 10];
  }
  __syncthreads();

  for (int idx = t; idx < NN * NS; idx += 192) {
    int a = idx >> 4, s = idx & 15, m = s >> 1;
    u32 odd = (u32)(s & 1);
    float sk = 0.f, sl = 0.f;
    for (int c = 0; c < NN; ++c) {
      u32 uk = T1p[c * NN + a][m];
      u32 ul = T1p[a * NN + c][m];
      sk += odd ? bfhi(uk) : bflo(uk);
      sl += odd ? bfhi(ul) : bflo(ul);
    }
    rk[a][s] = sk;
    rl[a][s] = sl;
  }
  __syncthreads();
  if (t < 16) {
    float v = 0.f;
    for (int a = 0; a < NN; ++a) v += rk[a][t];
    rkl[t] = v;
  }
  __syncthreads();
  for (int idx = t; idx < NN * NO; idx += 192) {
    int kk = idx >> 4, s2 = idx & 15;
    const float4* ck = (const float4*)(&c2kT[s2][0]);
    const float4* cl = (const float4*)(&c2lT[s2][0]);
    const float4* rkr = (const float4*)(&rk[kk][0]);
    const float4* rlr = (const float4*)(&rl[kk][0]);
    float ok = 0.f, ol = 0.f;
#pragma unroll
    for (int w = 0; w < 4; ++w) {
      float4 mk4 = ck[w], ml4 = cl[w], rk4 = rkr[w], rl4 = rlr[w];
      ok += mk4.x * rk4.x + mk4.y * rk4.y + mk4.z * rk4.z + mk4.w * rk4.w;
      ol += ml4.x * rl4.x + ml4.y * rl4.y + ml4.z * rl4.z + ml4.w * rl4.w;
    }
    Lt[kk][s2] = ok
               + mjkc[(size_t)((b * NN + i2) * NN + kk) * NS + s2]
               + mikc[(size_t)((b * NN + j) * NN + kk) * NS + s2]
               + mijkc[(size_t)(b * NN + kk) * NS + s2];
    Kt[kk][s2] = ol
               + mjlc[(size_t)((b * NN + i2) * NN + kk) * NS + s2]
               + milc[(size_t)((b * NN + j) * NN + kk) * NS + s2]
               + mijlc[(size_t)(b * NN + kk) * NS + s2];
  }
  if (t < NO) {
    float oq = 0.f;
#pragma unroll
    for (int s = 0; s < 16; ++s) oq += c2qT[t][s] * rkl[s];
    cterm[t] = oq
             + miklc[(size_t)(b * NN + j) * NS + t]
             + mjklc[(size_t)(b * NN + i2) * NS + t]
             + mijklc[(size_t)b * NS + t] + bias2[t];
    wl[t] = w_out[t];
  }
  __syncthreads();

  float acc0[16], acc1[16], acc2[16];
  auto initElem = [&](int c, u32 (&qa)[8], float (&acc)[16]) {
    const int kl = t + 192 * c;
    const int k = kl / NN, l = kl % NN;
    const uint4* pi = (const uint4*)(mic_p + ((size_t)((b * NN + j) * NKL + kl)) * 8);
    const uint4* pj = (const uint4*)(mjc_p + ((size_t)((b * NN + i2) * NKL + kl)) * 8);
    const float4* ps = (const float4*)(mijc + ((size_t)(b * NKL + kl)) * 16);
    uint4 i0 = pi[0], i1 = pi[1];
    uint4 j0 = pj[0], j1 = pj[1];
    float4 s0 = ps[0], s1 = ps[1], s2v = ps[2], s3 = ps[3];
    u32 ia[8] = {i0.x, i0.y, i0.z, i0.w, i1.x, i1.y, i1.z, i1.w};
    u32 ja[8] = {j0.x, j0.y, j0.z, j0.w, j1.x, j1.y, j1.z, j1.w};
    float sv[16];
    ((float4*)sv)[0] = s0; ((float4*)sv)[1] = s1; ((float4*)sv)[2] = s2v; ((float4*)sv)[3] = s3;
#pragma unroll
    for (int m = 0; m < 8; ++m) {
      acc[2 * m]     = cterm[2 * m]     + Kt[k][2 * m]     + Lt[l][2 * m]
                     + bflo(ia[m]) + bflo(ja[m]) + sv[2 * m];
      acc[2 * m + 1] = cterm[2 * m + 1] + Kt[k][2 * m + 1] + Lt[l][2 * m + 1]
                     + bfhi(ia[m]) + bfhi(ja[m]) + sv[2 * m + 1];
    }
  };
  initElem(0, qa0, acc0); initElem(1, qa1, acc1); initElem(2, qa2, acc2);

#pragma unroll
  for (int s = 0; s < 16; ++s) {
    const uint4* cp = (const uint4*)(c2p + s * 8);
    uint4 C0 = cp[0], C1 = cp[1];
    u32 ca[8] = {C0.x, C0.y, C0.z, C0.w, C1.x, C1.y, C1.z, C1.w};
    float row[16];
#pragma unroll
    for (int m = 0; m < 8; ++m) {
      row[2 * m] = bflo(ca[m]);
      row[2 * m + 1] = bfhi(ca[m]);
    }
    float v0 = (s & 1) ? bfhi(qa0[s >> 1]) : bflo(qa0[s >> 1]);
    float v1 = (s & 1) ? bfhi(qa1[s >> 1]) : bflo(qa1[s >> 1]);
    float v2 = (s & 1) ? bfhi(qa2[s >> 1]) : bflo(qa2[s >> 1]);
#pragma unroll
    for (int s2 = 0; s2 < 16; ++s2) {
      acc0[s2] += row[s2] * v0;
      acc1[s2] += row[s2] * v1;
      acc2[s2] += row[s2] * v2;
    }
  }
  float p = 0.f;
#pragma unroll
  for (int s2 = 0; s2 < 16; ++s2)
    p += wl[s2] * (fmaxf(acc0[s2], 0.f) + fmaxf(acc1[s2], 0.f) + fmaxf(acc2[s2], 0.f));
  for (int off = 32; off; off >>= 1) p += __shfl_down(p, off, 64);
  if ((t & 63) == 0) wsum[t >> 6] = p;
  __syncthreads();
  if (t == 0) pool_part[blk] = wsum[0] + wsum[1] + wsum[2];
}

// ---------------- K6: pooled partials -> out --------------------------------
__global__ __launch_bounds__(256) void k6_out(
    const float* __restrict__ pool_part, const float* __restrict__ b_out,
    float* __restrict__ out) {
  const int t = threadIdx.x;
  const int b = t >> 6, lane = t & 63;
  float v = 0.f;
  for (int c = lane; c < 576; c += 64) v += pool_part[b * 576 + c];
  for (int off = 32; off; off >>= 1) v += __shfl_down(v, off, 64);
  if (lane == 0) out[b] = v + b_out[0];
}

// ---------------- launch -----------------------------------------------------
extern "C" void kernel_launch(void* const* d_in, const int* in_sizes, int n_in,
                              void* d_out, int out_size, void* d_ws, size_t ws_size,
                              hipStream_t stream) {
  (void)in_sizes; (void)n_in; (void)out_size; (void)ws_size;
  const int*   xcat   = (const int*)d_in[0];
  const float* xfeat  = (const float*)d_in[1];
  const float* embed  = (const float*)d_in[2];
  const float* coefs1 = (const float*)d_in[3];
  const float* bias1  = (const float*)d_in[4];
  const float* coefs2 = (const float*)d_in[5];
  const float* bias2  = (const float*)d_in[6];
  const float* w_out  = (const float*)d_in[7];
  const float* b_out  = (const float*)d_in[8];
  float* out = (float*)d_out;
  char* ws = (char*)d_ws;

  u32*   T1g      = (u32*)(ws + 0);            // 42,467,328 B
  u32*   mi_p     = (u32*)(ws + 42467328);     // 1,769,472 B each
  u32*   mj_p     = (u32*)(ws + 44236800);
  u32*   mic_p    = (u32*)(ws + 46006272);
  u32*   mjc_p    = (u32*)(ws + 47775744);
  float* mijc     = (float*)(ws + 49545216);   // 147,456 B x5
  float* mikc     = (float*)(ws + 49692672);
  float* milc     = (float*)(ws + 49840128);
  float* mjkc     = (float*)(ws + 49987584);
  float* mjlc     = (float*)(ws + 50135040);
  float* mijkc    = (float*)(ws + 50282496);   // 6,144 B x4
  float* mijlc    = (float*)(ws + 50288640);
  float* miklc    = (float*)(ws + 50294784);
  float* mjklc    = (float*)(ws + 50300928);
  float* mijklc   = (float*)(ws + 50307072);   // 256 B
  float* quad_part= (float*)(ws + 50307328);   // 13,824 B (216 blk x 16)
  float* pool_part= (float*)(ws + 50321152);   // 9,216 B

  kb_eval<<<NB * NN * NN, 192, 0, stream>>>(xcat, xfeat, embed, coefs1, bias1, T1g);
  k3_marg<<<432, 256, 0, stream>>>(T1g, coefs2, mi_p, mj_p, mic_p, mjc_p, quad_part);
  kd_derived<<<745, 256, 0, stream>>>(mi_p, mj_p, quad_part, coefs2,
                                      mijc, mikc, milc, mjkc, mjlc,
                                      mijkc, mijlc, miklc, mjklc, mijklc);
  k5_final<<<NB * NN * NN, 192, 0, stream>>>(T1g, mic_p, mjc_p,
                                             mijc, mikc, milc, mjkc, mjlc,
                                             mijkc, mijlc, miklc, mjklc, mijklc,
                                             coefs2, bias2, w_out, pool_part);
  k6_out<<<1, 256, 0, stream>>>(pool_part, b_out, out);
}

// Round 14
// 88.673 us; speedup vs baseline: 1.1971x; 1.1147x over previous
//
#include <hip/hip_runtime.h>
#include <hip/hip_bf16.h>

// Eq4Net: permutation-equivariant 4th-order set network.
// T = x^{ox4} is rank-1 per channel: layer-1 pre-activations are
//   pre[s](k,l) = sum_d A_ij[s][d]*x_k[d]*x_l[d] + Bt_ij[k][s] + Gt2_ij[l][s].
// KB: per-tile eval (tables in LDS) -> T1 stored as fp8-e4m3 (16 B/elem,
//     per-tile scale in scale_g; hardware cvt, self-inverse encode/decode).
// K3: streams T1 twice for i/j marginals (raw + contracted, bf16-packed).
// KD: pair/triple/quad tables from packed marginals.
// K5: loads its tile once (fp8), computes tile-local marginals IN-BLOCK,
//     recombines all lookups + relu + pooled dot. K6 finishes.
// No contended atomics; 5 launches. T1 traffic halved vs bf16 (170->85 MB).

#define NB 4
#define NN 24
#define ND 16
#define NS 16
#define NO 16
#define NKL 576

typedef unsigned int u32;
typedef unsigned short u16;
typedef float f32x2 __attribute__((ext_vector_type(2)));

__device__ __forceinline__ u16 f2bf(float f) {
  u32 u = __float_as_uint(f);
  u = (u + 0x7fffu + ((u >> 16) & 1u)) >> 16;  // RNE
  return (u16)u;
}
__device__ __forceinline__ float bflo(u32 u) { return __uint_as_float(u << 16); }
__device__ __forceinline__ float bfhi(u32 u) { return __uint_as_float(u & 0xffff0000u); }
// decode 2 fp8 from the low 16 bits of w
__device__ __forceinline__ f32x2 dec2(u32 w) {
  return __builtin_amdgcn_cvt_pk_f32_fp8((int)w, false);
}
// encode 4 floats -> 4 fp8 in one u32
__device__ __forceinline__ u32 enc4(float a, float b, float c, float d) {
  u32 w = (u32)__builtin_amdgcn_cvt_pk_fp8_f32(a, b, 0, false);
  w = (u32)__builtin_amdgcn_cvt_pk_fp8_f32(c, d, (int)w, true);
  return w;
}

// ---------------- KB: eval -> fp8 T1 + per-tile scale ------------------------
// thread: l = t%24 (shared), k = t/24 + {0,8,16} -> kl = t, t+192, t+384.
__global__ __launch_bounds__(192, 2) void kb_eval(
    const int* __restrict__ xcat, const float* __restrict__ xfeat,
    const float* __restrict__ embed,
    const float* __restrict__ coefs1, const float* __restrict__ bias1,
    u32* __restrict__ T1g, float* __restrict__ scale_g) {
  const int blk = blockIdx.x;  // (b*24+i)*24+j
  const int j = blk % NN, i = (blk / NN) % NN, b = blk / (NN * NN);
  const int t = threadIdx.x;
  __shared__ float sx[NN * ND];
  __shared__ float SwL[16];
  __shared__ float Af[256], tb[256], tg[256], td[256];
  __shared__ float dconst[16];
  __shared__ __align__(16) float tabL[1152];  // A-pack | Bt | Gt2
  __shared__ float redm[3];

  for (int idx = t; idx < NN * ND; idx += 192) {
    int d = idx & 15, ii = idx >> 4;
    float v;
    if (d < 15) v = fmaxf(embed[xcat[b * NN + ii] * 15 + d], 0.f);
    else        v = xfeat[b * NN + ii];
    sx[idx] = v;
  }
  __syncthreads();
  if (t < 16) {
    float s = 0.f;
    for (int ii = 0; ii < NN; ++ii) s += sx[ii * 16 + t];
    SwL[t] = s;
  }
  __syncthreads();
  for (int idx = t; idx < 256; idx += 192) {  // idx = d*16+s
    int d = idx >> 4, s = idx & 15;
    const float* c = coefs1 + idx * 16;
    float xi = sx[i * 16 + d], xj = sx[j * 16 + d];
    float Sv = SwL[d];
    float S2 = Sv * Sv, S3 = S2 * Sv, S4 = S2 * S2, pij = xi * xj;
    Af[s * 16 + d] = c[0] * pij + c[1] * Sv * xj + c[2] * Sv * xi + c[5] * S2;
    tb[idx] = c[4] * Sv * pij + c[9] * S2 * xi + c[7] * S2 * xj + c[12] * S3;
    tg[idx] = c[3] * Sv * pij + c[8] * S2 * xi + c[6] * S2 * xj + c[11] * S3;
    td[idx] = c[10] * S2 * pij + c[14] * S3 * xi + c[13] * S3 * xj + c[15] * S4;
  }
  __syncthreads();
  if (t < 16) {
    float sd = 0.f;
    for (int d = 0; d < 16; ++d) sd += td[d * 16 + t];
    dconst[t] = sd + bias1[t];
  }
  __syncthreads();
  if (t < 128) {  // A bf16-pack from Af: s=t>>3, m=t&7
    int s = t >> 3, m = t & 7;
    tabL[t] = __uint_as_float((u32)f2bf(Af[s * 16 + 2 * m]) |
                              ((u32)f2bf(Af[s * 16 + 2 * m + 1]) << 16));
  }
  for (int idx = t; idx < 768; idx += 192) {
    int pos = idx >> 4, s = idx & 15;
    if (pos < NN) {  // Bt[k] -> [s*32 + (k%8)*4 + k/8]
      float acc = 0.f;
#pragma unroll
      for (int d = 0; d < 16; ++d) acc += tb[d * 16 + s] * sx[pos * 16 + d];
      tabL[128 + s * 32 + (pos % 8) * 4 + pos / 8] = acc;
    } else {         // Gt2[l] (+dconst) -> [s*32 + (l/3)*4 + l%3]
      int l = pos - NN;
      float acc = dconst[s];
#pragma unroll
      for (int d = 0; d < 16; ++d) acc += tg[d * 16 + s] * sx[l * 16 + d];
      tabL[640 + s * 32 + (l / 3) * 4 + l % 3] = acc;
    }
  }
  __syncthreads();

  const int l = t % NN, k0 = t / NN;  // elements k = k0, k0+8, k0+16
  const int lpos = (l / 3) * 4 + l % 3;
  float P0[16], P1[16], P2[16];
#pragma unroll
  for (int d = 0; d < 16; ++d) {
    float xl = sx[l * 16 + d];
    P0[d] = sx[k0 * 16 + d] * xl;
    P1[d] = sx[(k0 + 8) * 16 + d] * xl;
    P2[d] = sx[(k0 + 16) * 16 + d] * xl;
  }
  float pr0[16], pr1[16], pr2[16];
#pragma unroll
  for (int s = 0; s < 16; ++s) {
    const uint4* ap = (const uint4*)(tabL + s * 8);
    uint4 A0 = ap[0], A1 = ap[1];
    u32 qa[8] = {A0.x, A0.y, A0.z, A0.w, A1.x, A1.y, A1.z, A1.w};
    float Afr[16];
#pragma unroll
    for (int m = 0; m < 8; ++m) {
      Afr[2 * m] = bflo(qa[m]);
      Afr[2 * m + 1] = bfhi(qa[m]);
    }
    float4 vb4 = *(const float4*)(tabL + 128 + s * 32 + k0 * 4);
    float ct = tabL[640 + s * 32 + lpos];
    float v0 = vb4.x + ct, v1 = vb4.y + ct, v2 = vb4.z + ct;
#pragma unroll
    for (int d = 0; d < 16; ++d) {
      v0 += Afr[d] * P0[d];
      v1 += Afr[d] * P1[d];
      v2 += Afr[d] * P2[d];
    }
    pr0[s] = fmaxf(v0, 0.f);
    pr1[s] = fmaxf(v1, 0.f);
    pr2[s] = fmaxf(v2, 0.f);
  }
  // per-tile max -> scale (values are >= 0 post-relu)
  float tmax = 0.f;
#pragma unroll
  for (int s = 0; s < 16; ++s)
    tmax = fmaxf(tmax, fmaxf(pr0[s], fmaxf(pr1[s], pr2[s])));
  for (int off = 32; off; off >>= 1) tmax = fmaxf(tmax, __shfl_xor(tmax, off, 64));
  if ((t & 63) == 0) redm[t >> 6] = tmax;
  __syncthreads();
  float tilemax = fmaxf(redm[0], fmaxf(redm[1], redm[2]));
  float scale, scinv;
  if (tilemax > 1e-30f) { scale = 440.f / tilemax; scinv = tilemax / 440.f; }
  else                  { scale = 0.f; scinv = 0.f; }
  if (t == 0) scale_g[blk] = scinv;

  auto emit = [&](float (&pr)[16], int kl) {
    u32 w[4];
#pragma unroll
    for (int m = 0; m < 4; ++m)
      w[m] = enc4(pr[4 * m] * scale, pr[4 * m + 1] * scale,
                  pr[4 * m + 2] * scale, pr[4 * m + 3] * scale);
    *(uint4*)(T1g + ((size_t)blk * NKL + kl) * 4) = make_uint4(w[0], w[1], w[2], w[3]);
  };
  emit(pr0, t); emit(pr1, t + 192); emit(pr2, t + 384);
}

// ---------------- K3: m_i/m_j from fp8 T1 -> packed raw + contracted --------
__global__ __launch_bounds__(256) void k3_marg(
    const u32* __restrict__ T1g, const float* __restrict__ scale_g,
    const float* __restrict__ coefs2,
    u32* __restrict__ mi_p, u32* __restrict__ mj_p,
    u32* __restrict__ mic_p, u32* __restrict__ mjc_p,
    float* __restrict__ quad_part) {
  const int t = threadIdx.x, bb = blockIdx.x;
  const int pos = bb * 256 + t;       // 110592 total
  const bool isI = pos < 55296;       // block-uniform (216 blocks isI)
  const int p = isI ? pos : pos - 55296;
  __shared__ __align__(16) float ccT[16][20];  // [s2][s]
  __shared__ float qred[4][16];
  {
    int s = t >> 4, s2 = t & 15;
    ccT[s2][s] = coefs2[t * 16 + (isI ? 1 : 2)];
  }
  __syncthreads();
  const int ba = p / NKL, kl = p % NKL;
  const int b = ba / NN, a = ba % NN;
  const u32* base; size_t stride;
  if (isI) { base = T1g + ((size_t)(b * NN * NN + a) * NKL + kl) * 4; stride = (size_t)NN * NKL * 4; }
  else     { base = T1g + ((size_t)((b * NN + a) * NN) * NKL + kl) * 4; stride = (size_t)NKL * 4; }
  float raw[16];
#pragma unroll
  for (int s = 0; s < 16; ++s) raw[s] = 0.f;
#pragma unroll 4
  for (int c = 0; c < NN; ++c) {
    const uint4 q = *(const uint4*)(base + c * stride);
    const int tile = isI ? ((b * NN + c) * NN + a) : ((b * NN + a) * NN + c);
    const float sc = scale_g[tile];
    u32 qa[4] = {q.x, q.y, q.z, q.w};
#pragma unroll
    for (int m = 0; m < 4; ++m) {
      f32x2 d0 = dec2(qa[m]);
      f32x2 d1 = dec2(qa[m] >> 16);
      raw[4 * m]     += sc * d0.x;
      raw[4 * m + 1] += sc * d0.y;
      raw[4 * m + 2] += sc * d1.x;
      raw[4 * m + 3] += sc * d1.y;
    }
  }
  u32 rp[8], op[8];
#pragma unroll
  for (int m = 0; m < 8; ++m) {
    rp[m] = (u32)f2bf(raw[2 * m]) | ((u32)f2bf(raw[2 * m + 1]) << 16);
    float o0 = 0.f, o1 = 0.f;
#pragma unroll
    for (int w = 0; w < 4; ++w) {
      float4 m0 = ((const float4*)(&ccT[2 * m][0]))[w];
      float4 m1 = ((const float4*)(&ccT[2 * m + 1][0]))[w];
      o0 += m0.x * raw[4 * w] + m0.y * raw[4 * w + 1] + m0.z * raw[4 * w + 2] + m0.w * raw[4 * w + 3];
      o1 += m1.x * raw[4 * w] + m1.y * raw[4 * w + 1] + m1.z * raw[4 * w + 2] + m1.w * raw[4 * w + 3];
    }
    op[m] = (u32)f2bf(o0) | ((u32)f2bf(o1) << 16);
  }
  uint4* rdst = (uint4*)((isI ? mi_p : mj_p) + (size_t)p * 8);
  rdst[0] = make_uint4(rp[0], rp[1], rp[2], rp[3]);
  rdst[1] = make_uint4(rp[4], rp[5], rp[6], rp[7]);
  uint4* cdst = (uint4*)((isI ? mic_p : mjc_p) + (size_t)p * 8);
  cdst[0] = make_uint4(op[0], op[1], op[2], op[3]);
  cdst[1] = make_uint4(op[4], op[5], op[6], op[7]);
  if (isI) {
#pragma unroll
    for (int s = 0; s < 16; ++s) {
      float v = raw[s];
      for (int off = 32; off; off >>= 1) v += __shfl_xor(v, off, 64);
      raw[s] = v;
    }
    if ((t & 63) == 0) {
      int w = t >> 6;
#pragma unroll
      for (int s = 0; s < 16; ++s) qred[w][s] = raw[s];
    }
  }
  __syncthreads();
  if (isI && t < 16)
    quad_part[bb * 16 + t] = qred[0][t] + qred[1][t] + qred[2][t] + qred[3][t];
}

// ---------------- KD: pairs (360) + triples (384) + quad finisher (1) -------
__global__ __launch_bounds__(256) void kd_derived(
    const u32* __restrict__ mi_p, const u32* __restrict__ mj_p,
    const float* __restrict__ quad_part, const float* __restrict__ coefs2,
    float* __restrict__ mijc, float* __restrict__ mikc, float* __restrict__ milc,
    float* __restrict__ mjkc, float* __restrict__ mjlc,
    float* __restrict__ mijkc, float* __restrict__ mijlc,
    float* __restrict__ miklc, float* __restrict__ mjklc,
    float* __restrict__ mijklc) {
  const int bb = blockIdx.x, t = threadIdx.x;
  __shared__ float cc[256];
  __shared__ float ex[32][17];
  __shared__ float tot[16];
  __shared__ float qr[64];
  if (bb < 360) {  // pairs: 5 tables x 72 blocks; thread = (pp<32, m<8)
    int tbl = bb / 72;
    cc[t] = coefs2[t * 16 + 5 + tbl];
    int pp = t >> 3, m = t & 7;
    int pos = (bb % 72) * 32 + pp;
    int b = pos / 576, rem = pos % 576;
    const u32* srcb; int stride;
    if (tbl == 0) { srcb = mi_p + ((size_t)b * 24 * 576 + rem) * 8 + m; stride = 576 * 8; }
    else if (tbl == 1) { int jj = rem / 24, l = rem % 24;
      srcb = mi_p + (((size_t)(b * 24 + jj)) * 576 + l) * 8 + m; stride = 24 * 8; }
    else if (tbl == 2) { int jj = rem / 24, k = rem % 24;
      srcb = mi_p + (((size_t)(b * 24 + jj)) * 576 + k * 24) * 8 + m; stride = 8; }
    else if (tbl == 3) { int ii = rem / 24, l = rem % 24;
      srcb = mj_p + (((size_t)(b * 24 + ii)) * 576 + l) * 8 + m; stride = 24 * 8; }
    else { int ii = rem / 24, k = rem % 24;
      srcb = mj_p + (((size_t)(b * 24 + ii)) * 576 + k * 24) * 8 + m; stride = 8; }
    float v0 = 0.f, v1 = 0.f;
#pragma unroll 4
    for (int x = 0; x < 24; ++x) {
      u32 u = srcb[(size_t)x * stride];
      v0 += bflo(u); v1 += bfhi(u);
    }
    ex[pp][2 * m] = v0;
    ex[pp][2 * m + 1] = v1;
    __syncthreads();
    float* dst = (tbl == 0 ? mijc : tbl == 1 ? mikc : tbl == 2 ? milc : tbl == 3 ? mjkc : mjlc);
    for (int idx = t; idx < 512; idx += 256) {
      int pp2 = idx >> 4, s2 = idx & 15;
      float o = 0.f;
#pragma unroll
      for (int ss = 0; ss < 16; ++ss) o += cc[ss * 16 + s2] * ex[pp2][ss];
      dst[(size_t)((bb % 72) * 32 + pp2) * 16 + s2] = o;
    }
    return;
  }
  if (bb < 360 + 384) {  // triples: thread = (gg<32, m<8), 18 iters
    int idx = bb - 360;
    int tbl = idx / 96, rr = idx % 96;
    int b = rr / 24, a = rr % 24;
    cc[t] = coefs2[t * 16 + 11 + tbl];
    int gg = t >> 3, m = t & 7;
    const u32* src = (tbl == 3 ? mj_p : mi_p);
    float v0 = 0.f, v1 = 0.f;
#pragma unroll 2
    for (int it = 0; it < 18; ++it) {
      int u = gg + (it << 5);
      size_t addr;
      if (tbl == 0) { int j = u / 24, k = u % 24;
        addr = (((size_t)(b * 24 + j)) * 576 + k * 24 + a) * 8 + m; }
      else if (tbl == 1) { int j = u / 24, l = u % 24;
        addr = (((size_t)(b * 24 + j)) * 576 + a * 24 + l) * 8 + m; }
      else {
        addr = (((size_t)(b * 24 + a)) * 576 + u) * 8 + m; }
      u32 uu = src[addr];
      v0 += bflo(uu); v1 += bfhi(uu);
    }
    ex[gg][2 * m] = v0;
    ex[gg][2 * m + 1] = v1;
    __syncthreads();
    if (t < 16) {
      float w2 = 0.f;
#pragma unroll
      for (int g2 = 0; g2 < 32; ++g2) w2 += ex[g2][t];
      tot[t] = w2;
    }
    __syncthreads();
    if (t < 16) {
      float o = 0.f;
#pragma unroll
      for (int ss = 0; ss < 16; ++ss) o += cc[ss * 16 + t] * tot[ss];
      float* dst = (tbl == 0 ? mijkc : tbl == 1 ? mijlc : tbl == 2 ? miklc : mjklc);
      dst[(size_t)(b * 24 + a) * 16 + t] = o;
    }
    return;
  }
  // quad finisher: 54 block-partials per b
  if (t < 64) {
    int b = t >> 4, s = t & 15;
    float v = 0.f;
    for (int c = 0; c < 54; ++c) v += quad_part[(b * 54 + c) * 16 + s];
    qr[t] = v;
  }
  __syncthreads();
  if (t < 64) {
    int b = t >> 4, s2 = t & 15;
    float o = 0.f;
#pragma unroll
    for (int s = 0; s < 16; ++s) o += coefs2[(s * 16 + s2) * 16 + 15] * qr[b * 16 + s];
    mijklc[t] = o;
  }
}

// ---------------- K5: fp8 tile load + in-block marginals + layer2 + pool ----
__global__ __launch_bounds__(192, 2) void k5_final(
    const u32* __restrict__ T1g, const float* __restrict__ scale_g,
    const u32* __restrict__ mic_p, const u32* __restrict__ mjc_p,
    const float* __restrict__ mijc, const float* __restrict__ mikc,
    const float* __restrict__ milc, const float* __restrict__ mjkc,
    const float* __restrict__ mjlc,
    const float* __restrict__ mijkc, const float* __restrict__ mijlc,
    const float* __restrict__ miklc, const float* __restrict__ mjklc,
    const float* __restrict__ mijklc,
    const float* __restrict__ coefs2, const float* __restrict__ bias2,
    const float* __restrict__ w_out, float* __restrict__ pool_part) {
  const int orig = blockIdx.x;
  const int blk = (orig & 7) * 288 + (orig >> 3);  // XCD swizzle
  const int j = blk % NN, i2 = (blk / NN) % NN, b = blk / (NN * NN);
  const int t = threadIdx.x;
  __shared__ __align__(16) u32 c2p[128];
  __shared__ __align__(16) float c2kT[16][20], c2lT[16][20], c2qT[16][20];
  __shared__ u32 T1p[NKL][5];
  __shared__ __align__(16) float rk[NN][20], rl[NN][20];
  __shared__ __align__(16) float rkl[16];
  __shared__ __align__(16) float Kt[NN][16], Lt[NN][16];
  __shared__ __align__(16) float cterm[16], wl[16];
  __shared__ float wsum[3];

  const float sc = scale_g[blk];
  u32 qa0[4], qa1[4], qa2[4];
  auto loadT = [&](int c, u32 (&qa)[4]) {
    const int kl = t + 192 * c;
    const uint4 q = *(const uint4*)(T1g + ((size_t)blk * NKL + kl) * 4);
    qa[0] = q.x; qa[1] = q.y; qa[2] = q.z; qa[3] = q.w;
#pragma unroll
    for (int m = 0; m < 4; ++m) T1p[kl][m] = qa[m];
  };
  loadT(0, qa0); loadT(1, qa1); loadT(2, qa2);
  if (t < 128) {
    int s = t >> 3, m = t & 7;
    c2p[t] = (u32)f2bf(coefs2[(s * 16 + 2 * m) * 16]) |
             ((u32)f2bf(coefs2[(s * 16 + 2 * m + 1) * 16]) << 16);
  }
  for (int idx = t; idx < 256; idx += 192) {
    int s = idx >> 4, s2 = idx & 15;
    c2kT[s2][s] = coefs2[idx * 16 + 3];
    c2lT[s2][s] = coefs2[idx * 16 + 4];
    c2qT[s2][s] = coefs2[idx * 16 + 10];
  }
  __syncthreads();

  // tile-local marginals from fp8 LDS tile: 192 items = (a<24, pair<8)
  {
    int a = t >> 3, pr_ = t & 7, wIdx = pr_ >> 1;
    int sh = (pr_ & 1) * 16;
    float s0k = 0.f, s1k = 0.f, s0l = 0.f, s1l = 0.f;
    for (int c = 0; c < NN; ++c) {
      f32x2 dk = dec2(T1p[c * NN + a][wIdx] >> sh);
      f32x2 dl = dec2(T1p[a * NN + c][wIdx] >> sh);
      s0k += dk.x; s1k += dk.y;
      s0l += dl.x; s1l += dl.y;
    }
    rk[a][2 * pr_] = sc * s0k; rk[a][2 * pr_ + 1] = sc * s1k;
    rl[a][2 * pr_] = sc * s0l; rl[a][2 * pr_ + 1] = sc * s1l;
  }
  __syncthreads();
  if (t < 16) {
    float v = 0.f;
    for (int a = 0; a < NN; ++a) v += rk[a][t];
    rkl[t] = v;
  }
  __syncthreads();
  for (int idx = t; idx < NN * NO; idx += 192) {
    int kk = idx >> 4, s2 = idx & 15;
    const float4* ck = (const float4*)(&c2kT[s2][0]);
    const float4* cl = (const float4*)(&c2lT[s2][0]);
    const float4* rkr = (const float4*)(&rk[kk][0]);
    const float4* rlr = (const float4*)(&rl[kk][0]);
    float ok = 0.f, ol = 0.f;
#pragma unroll
    for (int w = 0; w < 4; ++w) {
      float4 mk4 = ck[w], ml4 = cl[w], rk4 = rkr[w], rl4 = rlr[w];
      ok += mk4.x * rk4.x + mk4.y * rk4.y + mk4.z * rk4.z + mk4.w * rk4.w;
      ol += ml4.x * rl4.x + ml4.y * rl4.y + ml4.z * rl4.z + ml4.w * rl4.w;
    }
    Lt[kk][s2] = ok
               + mjkc[(size_t)((b * NN + i2) * NN + kk) * NS + s2]
               + mikc[(size_t)((b * NN + j) * NN + kk) * NS + s2]
               + mijkc[(size_t)(b * NN + kk) * NS + s2];
    Kt[kk][s2] = ol
               + mjlc[(size_t)((b * NN + i2) * NN + kk) * NS + s2]
               + milc[(size_t)((b * NN + j) * NN + kk) * NS + s2]
               + mijlc[(size_t)(b * NN + kk) * NS + s2];
  }
  if (t < NO) {
    float oq = 0.f;
#pragma unroll
    for (int s = 0; s < 16; ++s) oq += c2qT[t][s] * rkl[s];
    cterm[t] = oq
             + miklc[(size_t)(b * NN + j) * NS + t]
             + mjklc[(size_t)(b * NN + i2) * NS + t]
             + mijklc[(size_t)b * NS + t] + bias2[t];
    wl[t] = w_out[t];
  }
  __syncthreads();

  float acc0[16], acc1[16], acc2[16];
  auto initElem = [&](int c, float (&acc)[16]) {
    const int kl = t + 192 * c;
    const int k = kl / NN, l = kl % NN;
    const uint4* pi = (const uint4*)(mic_p + ((size_t)((b * NN + j) * NKL + kl)) * 8);
    const uint4* pj = (const uint4*)(mjc_p + ((size_t)((b * NN + i2) * NKL + kl)) * 8);
    const float4* ps = (const float4*)(mijc + ((size_t)(b * NKL + kl)) * 16);
    uint4 i0 = pi[0], i1 = pi[1];
    uint4 j0 = pj[0], j1 = pj[1];
    float4 s0 = ps[0], s1 = ps[1], s2v = ps[2], s3 = ps[3];
    u32 ia[8] = {i0.x, i0.y, i0.z, i0.w, i1.x, i1.y, i1.z, i1.w};
    u32 ja[8] = {j0.x, j0.y, j0.z, j0.w, j1.x, j1.y, j1.z, j1.w};
    float sv[16];
    ((float4*)sv)[0] = s0; ((float4*)sv)[1] = s1; ((float4*)sv)[2] = s2v; ((float4*)sv)[3] = s3;
#pragma unroll
    for (int m = 0; m < 8; ++m) {
      acc[2 * m]     = cterm[2 * m]     + Kt[k][2 * m]     + Lt[l][2 * m]
                     + bflo(ia[m]) + bflo(ja[m]) + sv[2 * m];
      acc[2 * m + 1] = cterm[2 * m + 1] + Kt[k][2 * m + 1] + Lt[l][2 * m + 1]
                     + bfhi(ia[m]) + bfhi(ja[m]) + sv[2 * m + 1];
    }
  };
  initElem(0, acc0); initElem(1, acc1); initElem(2, acc2);

  // identity term: acc_c[s2] += sum_s c2id[s][s2] * T1_c[s]
#pragma unroll
  for (int s = 0; s < 16; ++s) {
    const uint4* cp = (const uint4*)(c2p + s * 8);
    uint4 C0 = cp[0], C1 = cp[1];
    u32 ca[8] = {C0.x, C0.y, C0.z, C0.w, C1.x, C1.y, C1.z, C1.w};
    float row[16];
#pragma unroll
    for (int m = 0; m < 8; ++m) {
      row[2 * m] = bflo(ca[m]);
      row[2 * m + 1] = bfhi(ca[m]);
    }
    f32x2 d0 = dec2(qa0[s >> 2] >> (((s >> 1) & 1) * 16));
    f32x2 d1 = dec2(qa1[s >> 2] >> (((s >> 1) & 1) * 16));
    f32x2 d2 = dec2(qa2[s >> 2] >> (((s >> 1) & 1) * 16));
    float v0 = ((s & 1) ? d0.y : d0.x) * sc;
    float v1 = ((s & 1) ? d1.y : d1.x) * sc;
    float v2 = ((s & 1) ? d2.y : d2.x) * sc;
#pragma unroll
    for (int s2 = 0; s2 < 16; ++s2) {
      acc0[s2] += row[s2] * v0;
      acc1[s2] += row[s2] * v1;
      acc2[s2] += row[s2] * v2;
    }
  }
  float p = 0.f;
#pragma unroll
  for (int s2 = 0; s2 < 16; ++s2)
    p += wl[s2] * (fmaxf(acc0[s2], 0.f) + fmaxf(acc1[s2], 0.f) + fmaxf(acc2[s2], 0.f));
  for (int off = 32; off; off >>= 1) p += __shfl_down(p, off, 64);
  if ((t & 63) == 0) wsum[t >> 6] = p;
  __syncthreads();
  if (t == 0) pool_part[blk] = wsum[0] + wsum[1] + wsum[2];
}

// ---------------- K6: pooled partials -> out --------------------------------
__global__ __launch_bounds__(256) void k6_out(
    const float* __restrict__ pool_part, const float* __restrict__ b_out,
    float* __restrict__ out) {
  const int t = threadIdx.x;
  const int b = t >> 6, lane = t & 63;
  float v = 0.f;
  for (int c = lane; c < 576; c += 64) v += pool_part[b * 576 + c];
  for (int off = 32; off; off >>= 1) v += __shfl_down(v, off, 64);
  if (lane == 0) out[b] = v + b_out[0];
}

// ---------------- launch -----------------------------------------------------
extern "C" void kernel_launch(void* const* d_in, const int* in_sizes, int n_in,
                              void* d_out, int out_size, void* d_ws, size_t ws_size,
                              hipStream_t stream) {
  (void)in_sizes; (void)n_in; (void)out_size; (void)ws_size;
  const int*   xcat   = (const int*)d_in[0];
  const float* xfeat  = (const float*)d_in[1];
  const float* embed  = (const float*)d_in[2];
  const float* coefs1 = (const float*)d_in[3];
  const float* bias1  = (const float*)d_in[4];
  const float* coefs2 = (const float*)d_in[5];
  const float* bias2  = (const float*)d_in[6];
  const float* w_out  = (const float*)d_in[7];
  const float* b_out  = (const float*)d_in[8];
  float* out = (float*)d_out;
  char* ws = (char*)d_ws;

  u32*   T1g      = (u32*)(ws + 0);            // 21,233,664 B (fp8)
  float* scale_g  = (float*)(ws + 21233664);   // 9,216 B
  u32*   mi_p     = (u32*)(ws + 21242880);     // 1,769,472 B each
  u32*   mj_p     = (u32*)(ws + 23012352);
  u32*   mic_p    = (u32*)(ws + 24781824);
  u32*   mjc_p    = (u32*)(ws + 26551296);
  float* mijc     = (float*)(ws + 28320768);   // 147,456 B x5
  float* mikc     = (float*)(ws + 28468224);
  float* milc     = (float*)(ws + 28615680);
  float* mjkc     = (float*)(ws + 28763136);
  float* mjlc     = (float*)(ws + 28910592);
  float* mijkc    = (float*)(ws + 29058048);   // 6,144 B x4
  float* mijlc    = (float*)(ws + 29064192);
  float* miklc    = (float*)(ws + 29070336);
  float* mjklc    = (float*)(ws + 29076480);
  float* mijklc   = (float*)(ws + 29082624);   // 256 B
  float* quad_part= (float*)(ws + 29082880);   // 13,824 B
  float* pool_part= (float*)(ws + 29096704);   // 9,216 B

  kb_eval<<<NB * NN * NN, 192, 0, stream>>>(xcat, xfeat, embed, coefs1, bias1,
                                            T1g, scale_g);
  k3_marg<<<432, 256, 0, stream>>>(T1g, scale_g, coefs2, mi_p, mj_p, mic_p,
                                   mjc_p, quad_part);
  kd_derived<<<745, 256, 0, stream>>>(mi_p, mj_p, quad_part, coefs2,
                                      mijc, mikc, milc, mjkc, mjlc,
                                      mijkc, mijlc, miklc, mjklc, mijklc);
  k5_final<<<NB * NN * NN, 192, 0, stream>>>(T1g, scale_g, mic_p, mjc_p,
                                             mijc, mikc, milc, mjkc, mjlc,
                                             mijkc, mijlc, miklc, mjklc, mijklc,
                                             coefs2, bias2, w_out, pool_part);
  k6_out<<<1, 256, 0, stream>>>(pool_part, b_out, out);
}

// Round 15
// 84.074 us; speedup vs baseline: 1.2626x; 1.0547x over previous
//
#include <hip/hip_runtime.h>
#include <hip/hip_bf16.h>

// Eq4Net: permutation-equivariant 4th-order set network.
// T = x^{ox4} is rank-1 per channel: layer-1 pre-activations are
//   pre[s](k,l) = sum_d A_ij[s][d]*x_k[d]*x_l[d] + Bt_ij[k][s] + Gt2_ij[l][s].
// KB: per-tile eval (tables in LDS, 4 barriers) -> T1 fp8-e4m3 + per-tile scale.
// K3: streams T1 twice for i/j marginals (raw + contracted, bf16-packed).
// KD: pair/triple/quad tables from packed marginals.
// K5: loads its tile once (fp8), computes tile-local marginals IN-BLOCK,
//     recombines all lookups + relu + pooled dot. K6 finishes.
// No contended atomics; 5 launches. T1 traffic halved vs bf16.

#define NB 4
#define NN 24
#define ND 16
#define NS 16
#define NO 16
#define NKL 576

typedef unsigned int u32;
typedef unsigned short u16;
typedef float f32x2 __attribute__((ext_vector_type(2)));

__device__ __forceinline__ u16 f2bf(float f) {
  u32 u = __float_as_uint(f);
  u = (u + 0x7fffu + ((u >> 16) & 1u)) >> 16;  // RNE
  return (u16)u;
}
__device__ __forceinline__ float bflo(u32 u) { return __uint_as_float(u << 16); }
__device__ __forceinline__ float bfhi(u32 u) { return __uint_as_float(u & 0xffff0000u); }
__device__ __forceinline__ f32x2 dec2(u32 w) {
  return __builtin_amdgcn_cvt_pk_f32_fp8((int)w, false);
}
__device__ __forceinline__ u32 enc4(float a, float b, float c, float d) {
  u32 w = (u32)__builtin_amdgcn_cvt_pk_fp8_f32(a, b, 0, false);
  w = (u32)__builtin_amdgcn_cvt_pk_fp8_f32(c, d, (int)w, true);
  return w;
}

// ---------------- KB: eval -> fp8 T1 + per-tile scale ------------------------
// thread: l = t%24 (shared), k = t/24 + {0,8,16} -> kl = t, t+192, t+384.
__global__ __launch_bounds__(192, 2) void kb_eval(
    const int* __restrict__ xcat, const float* __restrict__ xfeat,
    const float* __restrict__ embed,
    const float* __restrict__ coefs1, const float* __restrict__ bias1,
    u32* __restrict__ T1g, float* __restrict__ scale_g) {
  const int blk = blockIdx.x;  // (b*24+i)*24+j
  const int j = blk % NN, i = (blk / NN) % NN, b = blk / (NN * NN);
  const int t = threadIdx.x;
  __shared__ float sx[NN * ND];
  __shared__ float SwL[16];
  __shared__ float Af[256], tb[256], tg[256], td[256];
  __shared__ __align__(16) float tabL[1152];  // A-pack | Bt | Gt2
  __shared__ float redm[3];

  for (int idx = t; idx < NN * ND; idx += 192) {
    int d = idx & 15, ii = idx >> 4;
    float v;
    if (d < 15) v = fmaxf(embed[xcat[b * NN + ii] * 15 + d], 0.f);
    else        v = xfeat[b * NN + ii];
    sx[idx] = v;
  }
  __syncthreads();
  if (t < 16) {
    float s = 0.f;
    for (int ii = 0; ii < NN; ++ii) s += sx[ii * 16 + t];
    SwL[t] = s;
  }
  __syncthreads();
  for (int idx = t; idx < 256; idx += 192) {  // idx = d*16+s
    int d = idx >> 4, s = idx & 15;
    const float* c = coefs1 + idx * 16;
    float xi = sx[i * 16 + d], xj = sx[j * 16 + d];
    float Sv = SwL[d];
    float S2 = Sv * Sv, S3 = S2 * Sv, S4 = S2 * S2, pij = xi * xj;
    Af[s * 16 + d] = c[0] * pij + c[1] * Sv * xj + c[2] * Sv * xi + c[5] * S2;
    tb[idx] = c[4] * Sv * pij + c[9] * S2 * xi + c[7] * S2 * xj + c[12] * S3;
    tg[idx] = c[3] * Sv * pij + c[8] * S2 * xi + c[6] * S2 * xj + c[11] * S3;
    td[idx] = c[10] * S2 * pij + c[14] * S3 * xi + c[13] * S3 * xj + c[15] * S4;
  }
  __syncthreads();
  if (t < 128) {  // A bf16-pack from Af: s=t>>3, m=t&7
    int s = t >> 3, m = t & 7;
    tabL[t] = __uint_as_float((u32)f2bf(Af[s * 16 + 2 * m]) |
                              ((u32)f2bf(Af[s * 16 + 2 * m + 1]) << 16));
  }
  for (int idx = t; idx < 768; idx += 192) {
    int pos = idx >> 4, s = idx & 15;
    if (pos < NN) {  // Bt[k] -> [s*32 + (k%8)*4 + k/8]
      float acc = 0.f;
#pragma unroll
      for (int d = 0; d < 16; ++d) acc += tb[d * 16 + s] * sx[pos * 16 + d];
      tabL[128 + s * 32 + (pos % 8) * 4 + pos / 8] = acc;
    } else {         // Gt2[l] (+dconst folded) -> [s*32 + (l/3)*4 + l%3]
      int l = pos - NN;
      float acc = bias1[s];
#pragma unroll
      for (int d = 0; d < 16; ++d)
        acc += tg[d * 16 + s] * sx[l * 16 + d] + td[d * 16 + s];
      tabL[640 + s * 32 + (l / 3) * 4 + l % 3] = acc;
    }
  }
  __syncthreads();

  const int l = t % NN, k0 = t / NN;  // elements k = k0, k0+8, k0+16
  const int lpos = (l / 3) * 4 + l % 3;
  float P0[16], P1[16], P2[16];
#pragma unroll
  for (int d = 0; d < 16; ++d) {
    float xl = sx[l * 16 + d];
    P0[d] = sx[k0 * 16 + d] * xl;
    P1[d] = sx[(k0 + 8) * 16 + d] * xl;
    P2[d] = sx[(k0 + 16) * 16 + d] * xl;
  }
  float pr0[16], pr1[16], pr2[16];
#pragma unroll
  for (int s = 0; s < 16; ++s) {
    const uint4* ap = (const uint4*)(tabL + s * 8);
    uint4 A0 = ap[0], A1 = ap[1];
    u32 qa[8] = {A0.x, A0.y, A0.z, A0.w, A1.x, A1.y, A1.z, A1.w};
    float Afr[16];
#pragma unroll
    for (int m = 0; m < 8; ++m) {
      Afr[2 * m] = bflo(qa[m]);
      Afr[2 * m + 1] = bfhi(qa[m]);
    }
    float4 vb4 = *(const float4*)(tabL + 128 + s * 32 + k0 * 4);
    float ct = tabL[640 + s * 32 + lpos];
    float v0 = vb4.x + ct, v1 = vb4.y + ct, v2 = vb4.z + ct;
#pragma unroll
    for (int d = 0; d < 16; ++d) {
      v0 += Afr[d] * P0[d];
      v1 += Afr[d] * P1[d];
      v2 += Afr[d] * P2[d];
    }
    pr0[s] = fmaxf(v0, 0.f);
    pr1[s] = fmaxf(v1, 0.f);
    pr2[s] = fmaxf(v2, 0.f);
  }
  // per-tile max -> scale (values are >= 0 post-relu)
  float tmax = 0.f;
#pragma unroll
  for (int s = 0; s < 16; ++s)
    tmax = fmaxf(tmax, fmaxf(pr0[s], fmaxf(pr1[s], pr2[s])));
  for (int off = 32; off; off >>= 1) tmax = fmaxf(tmax, __shfl_xor(tmax, off, 64));
  if ((t & 63) == 0) redm[t >> 6] = tmax;
  __syncthreads();
  float tilemax = fmaxf(redm[0], fmaxf(redm[1], redm[2]));
  float scale, scinv;
  if (tilemax > 1e-30f) { scale = 440.f / tilemax; scinv = tilemax / 440.f; }
  else                  { scale = 0.f; scinv = 0.f; }
  if (t == 0) scale_g[blk] = scinv;

  auto emit = [&](float (&pr)[16], int kl) {
    u32 w[4];
#pragma unroll
    for (int m = 0; m < 4; ++m)
      w[m] = enc4(pr[4 * m] * scale, pr[4 * m + 1] * scale,
                  pr[4 * m + 2] * scale, pr[4 * m + 3] * scale);
    *(uint4*)(T1g + ((size_t)blk * NKL + kl) * 4) = make_uint4(w[0], w[1], w[2], w[3]);
  };
  emit(pr0, t); emit(pr1, t + 192); emit(pr2, t + 384);
}

// ---------------- K3: m_i/m_j from fp8 T1 -> packed raw + contracted --------
__global__ __launch_bounds__(256) void k3_marg(
    const u32* __restrict__ T1g, const float* __restrict__ scale_g,
    const float* __restrict__ coefs2,
    u32* __restrict__ mi_p, u32* __restrict__ mj_p,
    u32* __restrict__ mic_p, u32* __restrict__ mjc_p,
    float* __restrict__ quad_part) {
  const int t = threadIdx.x, bb = blockIdx.x;
  const int pos = bb * 256 + t;       // 110592 total
  const bool isI = pos < 55296;       // block-uniform (216 blocks isI)
  const int p = isI ? pos : pos - 55296;
  __shared__ __align__(16) float ccT[16][20];  // [s2][s]
  __shared__ float qred[4][16];
  {
    int s = t >> 4, s2 = t & 15;
    ccT[s2][s] = coefs2[t * 16 + (isI ? 1 : 2)];
  }
  __syncthreads();
  const int ba = p / NKL, kl = p % NKL;
  const int b = ba / NN, a = ba % NN;
  const u32* base; size_t stride;
  if (isI) { base = T1g + ((size_t)(b * NN * NN + a) * NKL + kl) * 4; stride = (size_t)NN * NKL * 4; }
  else     { base = T1g + ((size_t)((b * NN + a) * NN) * NKL + kl) * 4; stride = (size_t)NKL * 4; }
  float raw[16];
#pragma unroll
  for (int s = 0; s < 16; ++s) raw[s] = 0.f;
#pragma unroll 4
  for (int c = 0; c < NN; ++c) {
    const uint4 q = *(const uint4*)(base + c * stride);
    const int tile = isI ? ((b * NN + c) * NN + a) : ((b * NN + a) * NN + c);
    const float sc = scale_g[tile];
    u32 qa[4] = {q.x, q.y, q.z, q.w};
#pragma unroll
    for (int m = 0; m < 4; ++m) {
      f32x2 d0 = dec2(qa[m]);
      f32x2 d1 = dec2(qa[m] >> 16);
      raw[4 * m]     += sc * d0.x;
      raw[4 * m + 1] += sc * d0.y;
      raw[4 * m + 2] += sc * d1.x;
      raw[4 * m + 3] += sc * d1.y;
    }
  }
  u32 rp[8], op[8];
#pragma unroll
  for (int m = 0; m < 8; ++m) {
    rp[m] = (u32)f2bf(raw[2 * m]) | ((u32)f2bf(raw[2 * m + 1]) << 16);
    float o0 = 0.f, o1 = 0.f;
#pragma unroll
    for (int w = 0; w < 4; ++w) {
      float4 m0 = ((const float4*)(&ccT[2 * m][0]))[w];
      float4 m1 = ((const float4*)(&ccT[2 * m + 1][0]))[w];
      o0 += m0.x * raw[4 * w] + m0.y * raw[4 * w + 1] + m0.z * raw[4 * w + 2] + m0.w * raw[4 * w + 3];
      o1 += m1.x * raw[4 * w] + m1.y * raw[4 * w + 1] + m1.z * raw[4 * w + 2] + m1.w * raw[4 * w + 3];
    }
    op[m] = (u32)f2bf(o0) | ((u32)f2bf(o1) << 16);
  }
  uint4* rdst = (uint4*)((isI ? mi_p : mj_p) + (size_t)p * 8);
  rdst[0] = make_uint4(rp[0], rp[1], rp[2], rp[3]);
  rdst[1] = make_uint4(rp[4], rp[5], rp[6], rp[7]);
  uint4* cdst = (uint4*)((isI ? mic_p : mjc_p) + (size_t)p * 8);
  cdst[0] = make_uint4(op[0], op[1], op[2], op[3]);
  cdst[1] = make_uint4(op[4], op[5], op[6], op[7]);
  if (isI) {
#pragma unroll
    for (int s = 0; s < 16; ++s) {
      float v = raw[s];
      for (int off = 32; off; off >>= 1) v += __shfl_xor(v, off, 64);
      raw[s] = v;
    }
    if ((t & 63) == 0) {
      int w = t >> 6;
#pragma unroll
      for (int s = 0; s < 16; ++s) qred[w][s] = raw[s];
    }
  }
  __syncthreads();
  if (isI && t < 16)
    quad_part[bb * 16 + t] = qred[0][t] + qred[1][t] + qred[2][t] + qred[3][t];
}

// ---------------- KD: pairs (360) + triples (384) + quad finisher (1) -------
__global__ __launch_bounds__(256) void kd_derived(
    const u32* __restrict__ mi_p, const u32* __restrict__ mj_p,
    const float* __restrict__ quad_part, const float* __restrict__ coefs2,
    float* __restrict__ mijc, float* __restrict__ mikc, float* __restrict__ milc,
    float* __restrict__ mjkc, float* __restrict__ mjlc,
    float* __restrict__ mijkc, float* __restrict__ mijlc,
    float* __restrict__ miklc, float* __restrict__ mjklc,
    float* __restrict__ mijklc) {
  const int bb = blockIdx.x, t = threadIdx.x;
  __shared__ float cc[256];
  __shared__ float ex[32][17];
  __shared__ float tot[16];
  __shared__ float qr[64];
  if (bb < 360) {  // pairs: 5 tables x 72 blocks; thread = (pp<32, m<8)
    int tbl = bb / 72;
    cc[t] = coefs2[t * 16 + 5 + tbl];
    int pp = t >> 3, m = t & 7;
    int pos = (bb % 72) * 32 + pp;
    int b = pos / 576, rem = pos % 576;
    const u32* srcb; int stride;
    if (tbl == 0) { srcb = mi_p + ((size_t)b * 24 * 576 + rem) * 8 + m; stride = 576 * 8; }
    else if (tbl == 1) { int jj = rem / 24, l = rem % 24;
      srcb = mi_p + (((size_t)(b * 24 + jj)) * 576 + l) * 8 + m; stride = 24 * 8; }
    else if (tbl == 2) { int jj = rem / 24, k = rem % 24;
      srcb = mi_p + (((size_t)(b * 24 + jj)) * 576 + k * 24) * 8 + m; stride = 8; }
    else if (tbl == 3) { int ii = rem / 24, l = rem % 24;
      srcb = mj_p + (((size_t)(b * 24 + ii)) * 576 + l) * 8 + m; stride = 24 * 8; }
    else { int ii = rem / 24, k = rem % 24;
      srcb = mj_p + (((size_t)(b * 24 + ii)) * 576 + k * 24) * 8 + m; stride = 8; }
    float v0 = 0.f, v1 = 0.f;
#pragma unroll 4
    for (int x = 0; x < 24; ++x) {
      u32 u = srcb[(size_t)x * stride];
      v0 += bflo(u); v1 += bfhi(u);
    }
    ex[pp][2 * m] = v0;
    ex[pp][2 * m + 1] = v1;
    __syncthreads();
    float* dst = (tbl == 0 ? mijc : tbl == 1 ? mikc : tbl == 2 ? milc : tbl == 3 ? mjkc : mjlc);
    for (int idx = t; idx < 512; idx += 256) {
      int pp2 = idx >> 4, s2 = idx & 15;
      float o = 0.f;
#pragma unroll
      for (int ss = 0; ss < 16; ++ss) o += cc[ss * 16 + s2] * ex[pp2][ss];
      dst[(size_t)((bb % 72) * 32 + pp2) * 16 + s2] = o;
    }
    return;
  }
  if (bb < 360 + 384) {  // triples: thread = (gg<32, m<8), 18 iters
    int idx = bb - 360;
    int tbl = idx / 96, rr = idx % 96;
    int b = rr / 24, a = rr % 24;
    cc[t] = coefs2[t * 16 + 11 + tbl];
    int gg = t >> 3, m = t & 7;
    const u32* src = (tbl == 3 ? mj_p : mi_p);
    float v0 = 0.f, v1 = 0.f;
#pragma unroll 2
    for (int it = 0; it < 18; ++it) {
      int u = gg + (it << 5);
      size_t addr;
      if (tbl == 0) { int j = u / 24, k = u % 24;
        addr = (((size_t)(b * 24 + j)) * 576 + k * 24 + a) * 8 + m; }
      else if (tbl == 1) { int j = u / 24, l = u % 24;
        addr = (((size_t)(b * 24 + j)) * 576 + a * 24 + l) * 8 + m; }
      else {
        addr = (((size_t)(b * 24 + a)) * 576 + u) * 8 + m; }
      u32 uu = src[addr];
      v0 += bflo(uu); v1 += bfhi(uu);
    }
    ex[gg][2 * m] = v0;
    ex[gg][2 * m + 1] = v1;
    __syncthreads();
    if (t < 16) {
      float w2 = 0.f;
#pragma unroll
      for (int g2 = 0; g2 < 32; ++g2) w2 += ex[g2][t];
      tot[t] = w2;
    }
    __syncthreads();
    if (t < 16) {
      float o = 0.f;
#pragma unroll
      for (int ss = 0; ss < 16; ++ss) o += cc[ss * 16 + t] * tot[ss];
      float* dst = (tbl == 0 ? mijkc : tbl == 1 ? mijlc : tbl == 2 ? miklc : mjklc);
      dst[(size_t)(b * 24 + a) * 16 + t] = o;
    }
    return;
  }
  // quad finisher: 54 block-partials per b
  if (t < 64) {
    int b = t >> 4, s = t & 15;
    float v = 0.f;
    for (int c = 0; c < 54; ++c) v += quad_part[(b * 54 + c) * 16 + s];
    qr[t] = v;
  }
  __syncthreads();
  if (t < 64) {
    int b = t >> 4, s2 = t & 15;
    float o = 0.f;
#pragma unroll
    for (int s = 0; s < 16; ++s) o += coefs2[(s * 16 + s2) * 16 + 15] * qr[b * 16 + s];
    mijklc[t] = o;
  }
}

// ---------------- K5: fp8 tile load + in-block marginals + layer2 + pool ----
__global__ __launch_bounds__(192, 2) void k5_final(
    const u32* __restrict__ T1g, const float* __restrict__ scale_g,
    const u32* __restrict__ mic_p, const u32* __restrict__ mjc_p,
    const float* __restrict__ mijc, const float* __restrict__ mikc,
    const float* __restrict__ milc, const float* __restrict__ mjkc,
    const float* __restrict__ mjlc,
    const float* __restrict__ mijkc, const float* __restrict__ mijlc,
    const float* __restrict__ miklc, const float* __restrict__ mjklc,
    const float* __restrict__ mijklc,
    const float* __restrict__ coefs2, const float* __restrict__ bias2,
    const float* __restrict__ w_out, float* __restrict__ pool_part) {
  const int blk = blockIdx.x;  // no XCD swizzle: inputs are L3-resident
  const int j = blk % NN, i2 = (blk / NN) % NN, b = blk / (NN * NN);
  const int t = threadIdx.x;
  __shared__ __align__(16) u32 c2p[128];
  __shared__ __align__(16) float c2kT[16][20], c2lT[16][20], c2qT[16][20];
  __shared__ u32 T1p[NKL][5];
  __shared__ __align__(16) float rk[NN][20], rl[NN][20];
  __shared__ __align__(16) float rkl[16];
  __shared__ __align__(16) float Kt[NN][16], Lt[NN][16];
  __shared__ __align__(16) float cterm[16], wl[16];
  __shared__ float wsum[3];

  const float sc = scale_g[blk];
  u32 qa0[4], qa1[4], qa2[4];
  auto loadT = [&](int c, u32 (&qa)[4]) {
    const int kl = t + 192 * c;
    const uint4 q = *(const uint4*)(T1g + ((size_t)blk * NKL + kl) * 4);
    qa[0] = q.x; qa[1] = q.y; qa[2] = q.z; qa[3] = q.w;
#pragma unroll
    for (int m = 0; m < 4; ++m) T1p[kl][m] = qa[m];
  };
  loadT(0, qa0); loadT(1, qa1); loadT(2, qa2);
  if (t < 128) {
    int s = t >> 3, m = t & 7;
    c2p[t] = (u32)f2bf(coefs2[(s * 16 + 2 * m) * 16]) |
             ((u32)f2bf(coefs2[(s * 16 + 2 * m + 1) * 16]) << 16);
  }
  for (int idx = t; idx < 256; idx += 192) {
    int s = idx >> 4, s2 = idx & 15;
    c2kT[s2][s] = coefs2[idx * 16 + 3];
    c2lT[s2][s] = coefs2[idx * 16 + 4];
    c2qT[s2][s] = coefs2[idx * 16 + 10];
  }
  __syncthreads();

  // tile-local marginals from fp8 LDS tile: 192 items = (a<24, pair<8)
  {
    int a = t >> 3, pr_ = t & 7, wIdx = pr_ >> 1;
    int sh = (pr_ & 1) * 16;
    float s0k = 0.f, s1k = 0.f, s0l = 0.f, s1l = 0.f;
    for (int c = 0; c < NN; ++c) {
      f32x2 dk = dec2(T1p[c * NN + a][wIdx] >> sh);
      f32x2 dl = dec2(T1p[a * NN + c][wIdx] >> sh);
      s0k += dk.x; s1k += dk.y;
      s0l += dl.x; s1l += dl.y;
    }
    rk[a][2 * pr_] = sc * s0k; rk[a][2 * pr_ + 1] = sc * s1k;
    rl[a][2 * pr_] = sc * s0l; rl[a][2 * pr_ + 1] = sc * s1l;
  }
  __syncthreads();
  if (t < 16) {
    float v = 0.f;
    for (int a = 0; a < NN; ++a) v += rk[a][t];
    rkl[t] = v;
  }
  __syncthreads();
  for (int idx = t; idx < NN * NO; idx += 192) {
    int kk = idx >> 4, s2 = idx & 15;
    const float4* ck = (const float4*)(&c2kT[s2][0]);
    const float4* cl = (const float4*)(&c2lT[s2][0]);
    const float4* rkr = (const float4*)(&rk[kk][0]);
    const float4* rlr = (const float4*)(&rl[kk][0]);
    float ok = 0.f, ol = 0.f;
#pragma unroll
    for (int w = 0; w < 4; ++w) {
      float4 mk4 = ck[w], ml4 = cl[w], rk4 = rkr[w], rl4 = rlr[w];
      ok += mk4.x * rk4.x + mk4.y * rk4.y + mk4.z * rk4.z + mk4.w * rk4.w;
      ol += ml4.x * rl4.x + ml4.y * rl4.y + ml4.z * rl4.z + ml4.w * rl4.w;
    }
    Lt[kk][s2] = ok
               + mjkc[(size_t)((b * NN + i2) * NN + kk) * NS + s2]
               + mikc[(size_t)((b * NN + j) * NN + kk) * NS + s2]
               + mijkc[(size_t)(b * NN + kk) * NS + s2];
    Kt[kk][s2] = ol
               + mjlc[(size_t)((b * NN + i2) * NN + kk) * NS + s2]
               + milc[(size_t)((b * NN + j) * NN + kk) * NS + s2]
               + mijlc[(size_t)(b * NN + kk) * NS + s2];
  }
  if (t < NO) {
    float oq = 0.f;
#pragma unroll
    for (int s = 0; s < 16; ++s) oq += c2qT[t][s] * rkl[s];
    cterm[t] = oq
             + miklc[(size_t)(b * NN + j) * NS + t]
             + mjklc[(size_t)(b * NN + i2) * NS + t]
             + mijklc[(size_t)b * NS + t] + bias2[t];
    wl[t] = w_out[t];
  }
  __syncthreads();

  float acc0[16], acc1[16], acc2[16];
  auto initElem = [&](int c, float (&acc)[16]) {
    const int kl = t + 192 * c;
    const int k = kl / NN, l = kl % NN;
    const uint4* pi = (const uint4*)(mic_p + ((size_t)((b * NN + j) * NKL + kl)) * 8);
    const uint4* pj = (const uint4*)(mjc_p + ((size_t)((b * NN + i2) * NKL + kl)) * 8);
    const float4* ps = (const float4*)(mijc + ((size_t)(b * NKL + kl)) * 16);
    uint4 i0 = pi[0], i1 = pi[1];
    uint4 j0 = pj[0], j1 = pj[1];
    float4 s0 = ps[0], s1 = ps[1], s2v = ps[2], s3 = ps[3];
    u32 ia[8] = {i0.x, i0.y, i0.z, i0.w, i1.x, i1.y, i1.z, i1.w};
    u32 ja[8] = {j0.x, j0.y, j0.z, j0.w, j1.x, j1.y, j1.z, j1.w};
    float sv[16];
    ((float4*)sv)[0] = s0; ((float4*)sv)[1] = s1; ((float4*)sv)[2] = s2v; ((float4*)sv)[3] = s3;
#pragma unroll
    for (int m = 0; m < 8; ++m) {
      acc[2 * m]     = cterm[2 * m]     + Kt[k][2 * m]     + Lt[l][2 * m]
                     + bflo(ia[m]) + bflo(ja[m]) + sv[2 * m];
      acc[2 * m + 1] = cterm[2 * m + 1] + Kt[k][2 * m + 1] + Lt[l][2 * m + 1]
                     + bfhi(ia[m]) + bfhi(ja[m]) + sv[2 * m + 1];
    }
  };
  initElem(0, acc0); initElem(1, acc1); initElem(2, acc2);

  // identity term: acc_c[s2] += sum_s c2id[s][s2] * T1_c[s]
#pragma unroll
  for (int s = 0; s < 16; ++s) {
    const uint4* cp = (const uint4*)(c2p + s * 8);
    uint4 C0 = cp[0], C1 = cp[1];
    u32 ca[8] = {C0.x, C0.y, C0.z, C0.w, C1.x, C1.y, C1.z, C1.w};
    float row[16];
#pragma unroll
    for (int m = 0; m < 8; ++m) {
      row[2 * m] = bflo(ca[m]);
      row[2 * m + 1] = bfhi(ca[m]);
    }
    f32x2 d0 = dec2(qa0[s >> 2] >> (((s >> 1) & 1) * 16));
    f32x2 d1 = dec2(qa1[s >> 2] >> (((s >> 1) & 1) * 16));
    f32x2 d2 = dec2(qa2[s >> 2] >> (((s >> 1) & 1) * 16));
    float v0 = ((s & 1) ? d0.y : d0.x) * sc;
    float v1 = ((s & 1) ? d1.y : d1.x) * sc;
    float v2 = ((s & 1) ? d2.y : d2.x) * sc;
#pragma unroll
    for (int s2 = 0; s2 < 16; ++s2) {
      acc0[s2] += row[s2] * v0;
      acc1[s2] += row[s2] * v1;
      acc2[s2] += row[s2] * v2;
    }
  }
  float p = 0.f;
#pragma unroll
  for (int s2 = 0; s2 < 16; ++s2)
    p += wl[s2] * (fmaxf(acc0[s2], 0.f) + fmaxf(acc1[s2], 0.f) + fmaxf(acc2[s2], 0.f));
  for (int off = 32; off; off >>= 1) p += __shfl_down(p, off, 64);
  if ((t & 63) == 0) wsum[t >> 6] = p;
  __syncthreads();
  if (t == 0) pool_part[blk] = wsum[0] + wsum[1] + wsum[2];
}

// ---------------- K6: pooled partials -> out --------------------------------
__global__ __launch_bounds__(256) void k6_out(
    const float* __restrict__ pool_part, const float* __restrict__ b_out,
    float* __restrict__ out) {
  const int t = threadIdx.x;
  const int b = t >> 6, lane = t & 63;
  float v = 0.f;
  for (int c = lane; c < 576; c += 64) v += pool_part[b * 576 + c];
  for (int off = 32; off; off >>= 1) v += __shfl_down(v, off, 64);
  if (lane == 0) out[b] = v + b_out[0];
}

// ---------------- launch -----------------------------------------------------
extern "C" void kernel_launch(void* const* d_in, const int* in_sizes, int n_in,
                              void* d_out, int out_size, void* d_ws, size_t ws_size,
                              hipStream_t stream) {
  (void)in_sizes; (void)n_in; (void)out_size; (void)ws_size;
  const int*   xcat   = (const int*)d_in[0];
  const float* xfeat  = (const float*)d_in[1];
  const float* embed  = (const float*)d_in[2];
  const float* coefs1 = (const float*)d_in[3];
  const float* bias1  = (const float*)d_in[4];
  const float* coefs2 = (const float*)d_in[5];
  const float* bias2  = (const float*)d_in[6];
  const float* w_out  = (const float*)d_in[7];
  const float* b_out  = (const float*)d_in[8];
  float* out = (float*)d_out;
  char* ws = (char*)d_ws;

  u32*   T1g      = (u32*)(ws + 0);            // 21,233,664 B (fp8)
  float* scale_g  = (float*)(ws + 21233664);   // 9,216 B
  u32*   mi_p     = (u32*)(ws + 21242880);     // 1,769,472 B each
  u32*   mj_p     = (u32*)(ws + 23012352);
  u32*   mic_p    = (u32*)(ws + 24781824);
  u32*   mjc_p    = (u32*)(ws + 26551296);
  float* mijc     = (float*)(ws + 28320768);   // 147,456 B x5
  float* mikc     = (float*)(ws + 28468224);
  float* milc     = (float*)(ws + 28615680);
  float* mjkc     = (float*)(ws + 28763136);
  float* mjlc     = (float*)(ws + 28910592);
  float* mijkc    = (float*)(ws + 29058048);   // 6,144 B x4
  float* mijlc    = (float*)(ws + 29064192);
  float* miklc    = (float*)(ws + 29070336);
  float* mjklc    = (float*)(ws + 29076480);
  float* mijklc   = (float*)(ws + 29082624);   // 256 B
  float* quad_part= (float*)(ws + 29082880);   // 13,824 B
  float* pool_part= (float*)(ws + 29096704);   // 9,216 B

  kb_eval<<<NB * NN * NN, 192, 0, stream>>>(xcat, xfeat, embed, coefs1, bias1,
                                            T1g, scale_g);
  k3_marg<<<432, 256, 0, stream>>>(T1g, scale_g, coefs2, mi_p, mj_p, mic_p,
                                   mjc_p, quad_part);
  kd_derived<<<745, 256, 0, stream>>>(mi_p, mj_p, quad_part, coefs2,
                                      mijc, mikc, milc, mjkc, mjlc,
                                      mijkc, mijlc, miklc, mjklc, mijklc);
  k5_final<<<NB * NN * NN, 192, 0, stream>>>(T1g, scale_g, mic_p, mjc_p,
                                             mijc, mikc, milc, mjkc, mjlc,
                                             mijkc, mijlc, miklc, mjklc, mijklc,
                                             coefs2, bias2, w_out, pool_part);
  k6_out<<<1, 256, 0, stream>>>(pool_part, b_out, out);
}